// Round 7
// baseline (252.316 us; speedup 1.0000x reference)
//
#include <hip/hip_runtime.h>

typedef unsigned short u16;
typedef unsigned int u32;
typedef __attribute__((ext_vector_type(8))) short short8v;   // 8 x bf16 (raw bits)
typedef __attribute__((ext_vector_type(4))) float f32x4;
typedef __attribute__((ext_vector_type(2))) unsigned u32x2v;

#define DD 768
#define PP 1024
#define NTOK 4096

__device__ __forceinline__ u16 f2bf(float f) {
  u32 u = __builtin_bit_cast(u32, f);
  u += 0x7fffu + ((u >> 16) & 1u);
  return (u16)(u >> 16);
}
__device__ __forceinline__ float b2f(u16 v) {
  return __builtin_bit_cast(float, (u32)v << 16);
}
// pack hi16(fa)<<16 | hi16(fb) in ONE v_perm_b32 (truncating bf16 pack)
__device__ __forceinline__ u32 pk_trunc(float fa, float fb) {
  return __builtin_amdgcn_perm(__builtin_bit_cast(u32, fa), __builtin_bit_cast(u32, fb), 0x07060302u);
}
// extract element j of a bf16x8 register as float (j MUST be compile-time after unroll)
__device__ __forceinline__ float ex8(const short8v& v, int j) {
  const u32 dw = ((const u32*)&v)[j >> 1];
  return __builtin_bit_cast(float, (j & 1) ? (dw & 0xffff0000u) : (dw << 16));
}
__device__ __forceinline__ float dpp_shr1(float x) {   // lane i <- i-1
  return __builtin_bit_cast(float,
      __builtin_amdgcn_update_dpp(0, __builtin_bit_cast(int, x), 0x138, 0xf, 0xf, true));
}
__device__ __forceinline__ float dpp_shl1(float x) {   // lane i <- i+1
  return __builtin_bit_cast(float,
      __builtin_amdgcn_update_dpp(0, __builtin_bit_cast(int, x), 0x130, 0xf, 0xf, true));
}
__device__ __forceinline__ float xhalf_sum(float p) {  // p(lane) + p(lane^32), VALU pipe
#if __has_builtin(__builtin_amdgcn_permlane32_swap)
  u32x2v sw = __builtin_amdgcn_permlane32_swap(__builtin_bit_cast(u32, p),
                                               __builtin_bit_cast(u32, p), false, false);
  return __builtin_bit_cast(float, sw[0]) + __builtin_bit_cast(float, sw[1]);
#else
  return p + __shfl_xor(p, 32, 64);
#endif
}

// ---------------- fused: LayerNorm+shortcut  AND  all weight prep ----------------
__global__ __launch_bounds__(256) void prep_ln_k(const float* __restrict__ hs,
                                                 const float* __restrict__ gw, const float* __restrict__ gb,
                                                 u16* __restrict__ lnout, float* __restrict__ shortcut,
                                                 const float* __restrict__ win, u16* __restrict__ wInB,
                                                 const float* __restrict__ wout, u16* __restrict__ wOutB,
                                                 const float* __restrict__ wprj, u16* __restrict__ wPrjB,
                                                 const float* __restrict__ xdw, u16* __restrict__ wXdB,
                                                 const float* __restrict__ wup, const float* __restrict__ lup,
                                                 const float* __restrict__ uup, const float* __restrict__ dco,
                                                 u16* __restrict__ wB) {
  const int id = blockIdx.x;
  const int t = threadIdx.x;
  if (id < 4096) {                       // -------- LayerNorm on token id --------
    const int tok = id;
    const float* xr = hs + (size_t)tok * DD;
    float v0 = xr[t], v1 = xr[t + 256], v2 = xr[t + 512];
    float s = v0 + v1 + v2;
    float q = v0 * v0 + v1 * v1 + v2 * v2;
#pragma unroll
    for (int off = 32; off > 0; off >>= 1) {
      s += __shfl_down(s, off, 64);
      q += __shfl_down(q, off, 64);
    }
    __shared__ float ss[4], qs[4];
    const int wid = t >> 6, lane = t & 63;
    if (lane == 0) { ss[wid] = s; qs[wid] = q; }
    __syncthreads();
    const float st = ss[0] + ss[1] + ss[2] + ss[3];
    const float qt = qs[0] + qs[1] + qs[2] + qs[3];
    const float mu = st * (1.f / 768.f);
    const float var = qt * (1.f / 768.f) - mu * mu;
    const float rstd = rsqrtf(var + 1e-5f);
    float* sc = shortcut + (size_t)tok * DD;
    u16* lo = lnout + (size_t)tok * DD;
    sc[t] = v0; sc[t + 256] = v1; sc[t + 512] = v2;
    lo[t]       = f2bf((v0 - mu) * rstd * gw[t] + gb[t]);
    lo[t + 256] = f2bf((v1 - mu) * rstd * gw[t + 256] + gb[t + 256]);
    lo[t + 512] = f2bf((v2 - mu) * rstd * gw[t + 512] + gb[t + 512]);
    return;
  }
  const int id2 = id - 4096;
  if (id2 < 6912) {                      // -------- 3 x 589824 f32 -> bf16 --------
    const int m = id2 / 2304;
    const int i = (id2 - m * 2304) * 256 + t;
    const float* s = (m == 0) ? win : (m == 1) ? wout : wprj;
    u16* d = (m == 0) ? wInB : (m == 1) ? wOutB : wPrjB;
    d[i] = f2bf(s[i]);
  } else if (id2 < 7104) {               // -------- xdown 48x768 -> 64x768 padded --------
    const int i = (id2 - 6912) * 256 + t;
    const int r = i / DD;
    wXdB[i] = (r < 48) ? f2bf(xdw[i]) : (u16)0;
  } else {                               // -------- gather scan weights --------
    const int c = id2 - 7104;
    u16* dst = wB + (size_t)c * 2048;
    for (int i = t; i < 2048; i += 256) {
      const int row = i >> 6, s = i & 63;
      u16 v = 0;
      if (row < 24 && s < 48) {
        const int k = row & 3, type = row >> 2;
        const int ch = k * DD + c;
        const float* src;
        if (type < 3) src = wup + ((size_t)(type * 3072 + ch)) * 48;
        else if (type == 3) src = lup + (size_t)ch * 48;
        else if (type == 4) src = uup + (size_t)ch * 48;
        else src = dco + (size_t)ch * 48;
        v = f2bf(src[s]);
      }
      dst[i] = v;
    }
  }
}

// ---------------- LDS-FREE streaming GEMM (token-major B): out[o,pg] = sum_c A[o,c]*B[pg,c] ----
// Both operands K-contiguous -> per-lane b128 fragment loads are perfectly 64B-line-coalesced
// (lanes l15,16+l15,32+l15,48+l15 read one contiguous 64B line of one row). A is 1.2MB L2-hot;
// B re-read 12x2 = L2 traffic ~150MB @34.5TB/s. Zero LDS, zero barriers -> occupancy VGPR-bound,
// compiler free to pipeline. Ping-pong depth-2 register prefetch.
__global__ __launch_bounds__(256) void gemm_nl(const u16* __restrict__ A,
                                               const u16* __restrict__ Bt,
                                               void* __restrict__ outv, const int mode) {
  const int t = threadIdx.x;
  const int ntile = blockIdx.x * 128;
  const int mtile = blockIdx.y * 64;
  const int bb = ntile >> 10;
  const int wid = t >> 6, lane = t & 63;
  const int m0 = (wid & 1) * 32, n0 = (wid >> 1) * 64;
  const int l15 = lane & 15, quad = lane >> 4;
  f32x4 acc[2][4];
#pragma unroll
  for (int mi = 0; mi < 2; ++mi)
#pragma unroll
    for (int ni = 0; ni < 4; ++ni) acc[mi][ni] = (f32x4){0.f, 0.f, 0.f, 0.f};
  const u16* a0p = A + (size_t)(mtile + m0 + l15) * DD + quad * 8;
  const u16* a1p = a0p + (size_t)16 * DD;
  const u16* b0p = Bt + (size_t)(ntile + n0 + l15) * DD + quad * 8;
  const u16* b1p = b0p + (size_t)16 * DD;
  const u16* b2p = b0p + (size_t)32 * DD;
  const u16* b3p = b0p + (size_t)48 * DD;
  short8v a0e, a1e, b0e, b1e, b2e, b3e;
  short8v a0o, a1o, b0o, b1o, b2o, b3o;
#define LOADE(k0)                                              \
  {                                                            \
    a0e = *reinterpret_cast<const short8v*>(a0p + (k0));       \
    a1e = *reinterpret_cast<const short8v*>(a1p + (k0));       \
    b0e = *reinterpret_cast<const short8v*>(b0p + (k0));       \
    b1e = *reinterpret_cast<const short8v*>(b1p + (k0));       \
    b2e = *reinterpret_cast<const short8v*>(b2p + (k0));       \
    b3e = *reinterpret_cast<const short8v*>(b3p + (k0));       \
  }
#define LOADO(k0)                                              \
  {                                                            \
    a0o = *reinterpret_cast<const short8v*>(a0p + (k0));       \
    a1o = *reinterpret_cast<const short8v*>(a1p + (k0));       \
    b0o = *reinterpret_cast<const short8v*>(b0p + (k0));       \
    b1o = *reinterpret_cast<const short8v*>(b1p + (k0));       \
    b2o = *reinterpret_cast<const short8v*>(b2p + (k0));       \
    b3o = *reinterpret_cast<const short8v*>(b3p + (k0));       \
  }
  LOADE(0);
  for (int k0 = 0; k0 < DD; k0 += 64) {
    LOADO(k0 + 32);
    acc[0][0] = __builtin_amdgcn_mfma_f32_16x16x32_bf16(a0e, b0e, acc[0][0], 0, 0, 0);
    acc[0][1] = __builtin_amdgcn_mfma_f32_16x16x32_bf16(a0e, b1e, acc[0][1], 0, 0, 0);
    acc[0][2] = __builtin_amdgcn_mfma_f32_16x16x32_bf16(a0e, b2e, acc[0][2], 0, 0, 0);
    acc[0][3] = __builtin_amdgcn_mfma_f32_16x16x32_bf16(a0e, b3e, acc[0][3], 0, 0, 0);
    acc[1][0] = __builtin_amdgcn_mfma_f32_16x16x32_bf16(a1e, b0e, acc[1][0], 0, 0, 0);
    acc[1][1] = __builtin_amdgcn_mfma_f32_16x16x32_bf16(a1e, b1e, acc[1][1], 0, 0, 0);
    acc[1][2] = __builtin_amdgcn_mfma_f32_16x16x32_bf16(a1e, b2e, acc[1][2], 0, 0, 0);
    acc[1][3] = __builtin_amdgcn_mfma_f32_16x16x32_bf16(a1e, b3e, acc[1][3], 0, 0, 0);
    if (k0 + 64 < DD) LOADE(k0 + 64);
    acc[0][0] = __builtin_amdgcn_mfma_f32_16x16x32_bf16(a0o, b0o, acc[0][0], 0, 0, 0);
    acc[0][1] = __builtin_amdgcn_mfma_f32_16x16x32_bf16(a0o, b1o, acc[0][1], 0, 0, 0);
    acc[0][2] = __builtin_amdgcn_mfma_f32_16x16x32_bf16(a0o, b2o, acc[0][2], 0, 0, 0);
    acc[0][3] = __builtin_amdgcn_mfma_f32_16x16x32_bf16(a0o, b3o, acc[0][3], 0, 0, 0);
    acc[1][0] = __builtin_amdgcn_mfma_f32_16x16x32_bf16(a1o, b0o, acc[1][0], 0, 0, 0);
    acc[1][1] = __builtin_amdgcn_mfma_f32_16x16x32_bf16(a1o, b1o, acc[1][1], 0, 0, 0);
    acc[1][2] = __builtin_amdgcn_mfma_f32_16x16x32_bf16(a1o, b2o, acc[1][2], 0, 0, 0);
    acc[1][3] = __builtin_amdgcn_mfma_f32_16x16x32_bf16(a1o, b3o, acc[1][3], 0, 0, 0);
  }
#undef LOADE
#undef LOADO
#pragma unroll
  for (int mi = 0; mi < 2; ++mi) {
#pragma unroll
    for (int ni = 0; ni < 4; ++ni) {
      const int ob = mtile + m0 + mi * 16 + quad * 4;
      const int pg = ntile + n0 + ni * 16 + l15;
      if (mode == 1) {
        *reinterpret_cast<f32x4*>((float*)outv + (size_t)pg * DD + ob) = acc[mi][ni];
      } else {
        const int pq = pg & 1023;
        u16* dstb = (u16*)outv;
#pragma unroll
        for (int r = 0; r < 4; ++r)
          dstb[((size_t)(bb * DD + ob + r)) * PP + pq] = f2bf(acc[mi][ni][r]);
      }
    }
  }
}

// ---------------- channel-major-B GEMM: A direct from L2, B via LDS transpose ----------------
// A-frags (weights, L2-hot) read straight from global (perfectly line-coalesced) -> LDS reads
// drop 12->8 per wave-iter, A-staging gone. B staged with uint2 (4-channel) writes, prefetched.
__global__ __launch_bounds__(256) void gemm_cm(const u16* __restrict__ A,
                                               const u16* __restrict__ Bt,
                                               void* __restrict__ outv, const int mode) {
  __shared__ u16 BlF[144 * 72];   // 20,736 B  row-permuted: phys = tok + (tok>>3)
  const int t = threadIdx.x;
  const int ntile = blockIdx.x * 128;
  const int mtile = blockIdx.y * 64;
  const int bb = ntile >> 10, pq0 = ntile & 1023;
  const int wid = t >> 6, lane = t & 63;
  const int m0 = (wid & 1) * 32, n0 = (wid >> 1) * 64;
  const int l15 = lane & 15, quad = lane >> 4;
  f32x4 acc[2][4];
#pragma unroll
  for (int mi = 0; mi < 2; ++mi)
#pragma unroll
    for (int ni = 0; ni < 4; ++ni) acc[mi][ni] = (f32x4){0.f, 0.f, 0.f, 0.f};
  // B staging ids: thread owns channels 4chp..4chp+3, tokens tok0..tok0+7
  const int chp = t >> 4, tok0 = (t & 15) * 8;
  const u16* bgc = Bt + ((size_t)(bb * DD + chp * 4)) * PP + pq0 + tok0;
  // A direct fragment pointers
  const u16* a0p = A + (size_t)(mtile + m0 + l15) * DD + quad * 8;
  const u16* a1p = a0p + (size_t)16 * DD;
  uint4 pb0, pb1, pb2, pb3;
  short8v paf[2][2];
#define LOADB(k0)                                                            \
  {                                                                          \
    pb0 = *reinterpret_cast<const uint4*>(bgc + (size_t)(k0) * PP);          \
    pb1 = *reinterpret_cast<const uint4*>(bgc + (size_t)((k0) + 1) * PP);    \
    pb2 = *reinterpret_cast<const uint4*>(bgc + (size_t)((k0) + 2) * PP);    \
    pb3 = *reinterpret_cast<const uint4*>(bgc + (size_t)((k0) + 3) * PP);    \
  }
#define LOADA(k0)                                                            \
  {                                                                          \
    paf[0][0] = *reinterpret_cast<const short8v*>(a0p + (k0));               \
    paf[0][1] = *reinterpret_cast<const short8v*>(a0p + (k0) + 32);          \
    paf[1][0] = *reinterpret_cast<const short8v*>(a1p + (k0));               \
    paf[1][1] = *reinterpret_cast<const short8v*>(a1p + (k0) + 32);          \
  }
  LOADB(0);
  LOADA(0);
  for (int k0 = 0; k0 < DD; k0 += 64) {
    __syncthreads();                     // prev compute done reading BlF
    {
      union { uint4 v; u16 u[8]; } ua, ub, uc, ud;
      ua.v = pb0; ub.v = pb1; uc.v = pb2; ud.v = pb3;
#pragma unroll
      for (int i2 = 0; i2 < 8; ++i2) {
        const int tk = tok0 + i2;
        const int prow = (tk + (tk >> 3)) * 72;
        *reinterpret_cast<uint2*>(&BlF[prow + chp * 4]) =
            make_uint2((u32)ua.u[i2] | ((u32)ub.u[i2] << 16),
                       (u32)uc.u[i2] | ((u32)ud.u[i2] << 16));
      }
    }
    __syncthreads();                     // LDS ready
    short8v af[2][2];
#pragma unroll
    for (int mi = 0; mi < 2; ++mi)
#pragma unroll
      for (int ks = 0; ks < 2; ++ks) af[mi][ks] = paf[mi][ks];
    if (k0 + 64 < DD) { LOADB(k0 + 64); LOADA(k0 + 64); }   // fly under compute
    short8v bfr[4][2];
#pragma unroll
    for (int ni = 0; ni < 4; ++ni) {
      const int tl = n0 + ni * 16 + l15;
      const int prow = (tl + (tl >> 3)) * 72;
#pragma unroll
      for (int ks = 0; ks < 2; ++ks)
        bfr[ni][ks] = *reinterpret_cast<const short8v*>(&BlF[prow + ks * 32 + quad * 8]);
    }
#pragma unroll
    for (int mi = 0; mi < 2; ++mi)
#pragma unroll
      for (int ni = 0; ni < 4; ++ni) {
        acc[mi][ni] = __builtin_amdgcn_mfma_f32_16x16x32_bf16(af[mi][0], bfr[ni][0], acc[mi][ni], 0, 0, 0);
        acc[mi][ni] = __builtin_amdgcn_mfma_f32_16x16x32_bf16(af[mi][1], bfr[ni][1], acc[mi][ni], 0, 0, 0);
      }
  }
#undef LOADB
#undef LOADA
#pragma unroll
  for (int mi = 0; mi < 2; ++mi) {
#pragma unroll
    for (int ni = 0; ni < 4; ++ni) {
      const int ob = mtile + m0 + mi * 16 + quad * 4;
      const int pg = ntile + n0 + ni * 16 + l15;
      if (mode == 1) {
        *reinterpret_cast<f32x4*>((float*)outv + (size_t)pg * DD + ob) = acc[mi][ni];
      } else {
        const int pq = pg & 1023;
        u16* dstb = (u16*)outv;
#pragma unroll
        for (int r = 0; r < 4; ++r)
          dstb[((size_t)(bb * DD + ob + r)) * PP + pq] = f2bf(acc[mi][ni][r]);
      }
    }
  }
}

// ---------------- xdown GEMM: xpA[(b*1024+i)*64 + coef] from channel-major y2 ----------------
// grid 256: 16-token N-tiles. A = wXdB 64x768 (rows 48+ zero), i = ((p&31)>>4)*512 + (p>>5)*16 + (p&15)
__global__ __launch_bounds__(256) void xdgemm_k(const u16* __restrict__ A,
                                                const u16* __restrict__ Ycm,
                                                u16* __restrict__ xpA) {
  __shared__ u16 Al[64][72];
  __shared__ u16 Bl[16][72];
  const int t = threadIdx.x;
  const int ntile = blockIdx.x * 16;
  const int bb = ntile >> 10, pq0 = ntile & 1023;
  const int wid = t >> 6, lane = t & 63, l15 = lane & 15, quad = lane >> 4;
  f32x4 acc = (f32x4){0.f, 0.f, 0.f, 0.f};
  const int arow = t >> 2, aks = (t & 3) * 16;
  const u16* ag = A + (size_t)arow * DD + aks;
  const int chp = t >> 3;          // 0..31 channel-pairs (ch = 2*chp)
  const int tk0 = (t & 7) * 2;     // tokens tk0, tk0+1
  const u16* bg0 = Ycm + ((size_t)(bb * DD + chp * 2)) * PP + pq0 + tk0;
  for (int k0 = 0; k0 < DD; k0 += 64) {
    const uint4 a0 = *reinterpret_cast<const uint4*>(ag + k0);
    const uint4 a1 = *reinterpret_cast<const uint4*>(ag + k0 + 8);
    const u32 b0 = *reinterpret_cast<const u32*>(bg0 + (size_t)k0 * PP);
    const u32 b1 = *reinterpret_cast<const u32*>(bg0 + (size_t)(k0 + 1) * PP);
    __syncthreads();
    *reinterpret_cast<uint4*>(&Al[arow][aks]) = a0;
    *reinterpret_cast<uint4*>(&Al[arow][aks + 8]) = a1;
    *reinterpret_cast<u32*>(&Bl[tk0][chp * 2]) = (b0 & 0xffffu) | (b1 << 16);
    *reinterpret_cast<u32*>(&Bl[tk0 + 1][chp * 2]) = (b0 >> 16) | (b1 & 0xffff0000u);
    __syncthreads();
#pragma unroll
    for (int ks = 0; ks < 2; ++ks) {
      const short8v af = *reinterpret_cast<const short8v*>(&Al[wid * 16 + l15][ks * 32 + quad * 8]);
      const short8v bf = *reinterpret_cast<const short8v*>(&Bl[l15][ks * 32 + quad * 8]);
      acc = __builtin_amdgcn_mfma_f32_16x16x32_bf16(af, bf, acc, 0, 0, 0);
    }
  }
  const int pq = pq0 + l15;
  const int i = ((pq & 31) >> 4) * 512 + (pq >> 5) * 16 + (pq & 15);
  u16* dst = xpA + ((size_t)(bb * 1024 + i)) * 64 + wid * 16 + quad * 4;
  *reinterpret_cast<uint2*>(dst) = make_uint2(pk_trunc(acc[1], acc[0]), pk_trunc(acc[3], acc[2]));
}

// ---------------- depthwise 7x7 + bias, bf16 -> bf16 ----------------
__global__ __launch_bounds__(256) void dwconv7_k(const u16* __restrict__ x,
                                                 const float* __restrict__ wgt,
                                                 const float* __restrict__ bias,
                                                 u16* __restrict__ y) {
  const int bc = blockIdx.x;
  const int c = bc % DD;
  __shared__ float tile[38 * 38];
  __shared__ float wl[49];
  __shared__ float bsh[1];
  const int t = threadIdx.x;
  for (int i = t; i < 38 * 38; i += 256) tile[i] = 0.f;
  __syncthreads();
  const u16* xr = x + (size_t)bc * PP;
  for (int i = t; i < 512; i += 256) {
    const u32 v = reinterpret_cast<const u32*>(xr)[i];
    const int p0 = i * 2;
    const int h = p0 >> 5, w = p0 & 31;
    tile[(h + 3) * 38 + w + 3] = b2f((u16)v);
    tile[(h + 3) * 38 + w + 4] = b2f((u16)(v >> 16));
  }
  if (t < 49) wl[t] = wgt[c * 49 + t];
  if (t == 0) bsh[0] = bias[c];
  __syncthreads();
  u16* yo = y + (size_t)bc * PP;
  const int w = t & 31, hb = t >> 5;         // hb 0..7 -> rows hb*4 .. hb*4+3
  const float bv = bsh[0];
  float a0 = bv, a1 = bv, a2 = bv, a3 = bv;
#pragma unroll
  for (int rr = 0; rr < 10; ++rr) {          // input rows hb*4+rr
    float row[7];
#pragma unroll
    for (int kw = 0; kw < 7; ++kw) row[kw] = tile[(hb * 4 + rr) * 38 + w + kw];
    if (rr < 7) {
#pragma unroll
      for (int kw = 0; kw < 7; ++kw) a0 = fmaf(wl[rr * 7 + kw], row[kw], a0);
    }
    if (rr >= 1 && rr < 8) {
#pragma unroll
      for (int kw = 0; kw < 7; ++kw) a1 = fmaf(wl[(rr - 1) * 7 + kw], row[kw], a1);
    }
    if (rr >= 2 && rr < 9) {
#pragma unroll
      for (int kw = 0; kw < 7; ++kw) a2 = fmaf(wl[(rr - 2) * 7 + kw], row[kw], a2);
    }
    if (rr >= 3) {
#pragma unroll
      for (int kw = 0; kw < 7; ++kw) a3 = fmaf(wl[(rr - 3) * 7 + kw], row[kw], a3);
    }
  }
  yo[(hb * 4 + 0) * 32 + w] = f2bf(a0);
  yo[(hb * 4 + 1) * 32 + w] = f2bf(a1);
  yo[(hb * 4 + 2) * 32 + w] = f2bf(a2);
  yo[(hb * 4 + 3) * 32 + w] = f2bf(a3);
}

// ---------------- depthwise 3x3 (no bias) + x*relu(x), bf16 -> bf16 ----------------
__global__ __launch_bounds__(256) void dwconv3_k(const u16* __restrict__ x,
                                                 const float* __restrict__ wgt,
                                                 u16* __restrict__ y) {
  const int bc = blockIdx.x;
  const int c = bc % DD;
  __shared__ float tile[34 * 34];
  __shared__ float wl[9];
  const int t = threadIdx.x;
  for (int i = t; i < 34 * 34; i += 256) tile[i] = 0.f;
  __syncthreads();
  const u16* xr = x + (size_t)bc * PP;
  for (int i = t; i < 512; i += 256) {
    const u32 v = reinterpret_cast<const u32*>(xr)[i];
    const int p0 = i * 2;
    const int h = p0 >> 5, w = p0 & 31;
    tile[(h + 1) * 34 + w + 1] = b2f((u16)v);
    tile[(h + 1) * 34 + w + 2] = b2f((u16)(v >> 16));
  }
  if (t < 9) wl[t] = wgt[c * 9 + t];
  __syncthreads();
  u16* yo = y + (size_t)bc * PP;
  const int w = t & 31, hb = t >> 5;
  float a0 = 0.f, a1 = 0.f, a2 = 0.f, a3 = 0.f;
#pragma unroll
  for (int rr = 0; rr < 6; ++rr) {
    float row[3];
#pragma unroll
    for (int kw = 0; kw < 3; ++kw) row[kw] = tile[(hb * 4 + rr) * 34 + w + kw];
    if (rr < 3) {
#pragma unroll
      for (int kw = 0; kw < 3; ++kw) a0 = fmaf(wl[rr * 3 + kw], row[kw], a0);
    }
    if (rr >= 1 && rr < 4) {
#pragma unroll
      for (int kw = 0; kw < 3; ++kw) a1 = fmaf(wl[(rr - 1) * 3 + kw], row[kw], a1);
    }
    if (rr >= 2 && rr < 5) {
#pragma unroll
      for (int kw = 0; kw < 3; ++kw) a2 = fmaf(wl[(rr - 2) * 3 + kw], row[kw], a2);
    }
    if (rr >= 3) {
#pragma unroll
      for (int kw = 0; kw < 3; ++kw) a3 = fmaf(wl[(rr - 3) * 3 + kw], row[kw], a3);
    }
  }
  const float r0 = a0 > 0.f ? a0 * a0 : 0.f;
  const float r1 = a1 > 0.f ? a1 * a1 : 0.f;
  const float r2 = a2 > 0.f ? a2 * a2 : 0.f;
  const float r3 = a3 > 0.f ? a3 * a3 : 0.f;
  yo[(hb * 4 + 0) * 32 + w] = f2bf(r0);
  yo[(hb * 4 + 1) * 32 + w] = f2bf(r1);
  yo[(hb * 4 + 2) * 32 + w] = f2bf(r2);
  yo[(hb * 4 + 3) * 32 + w] = f2bf(r3);
}

// ---------------- producer/consumer fused scan (R4 structure + setprio) ----------------
#define ACT_SWZ(row, col) ((col) ^ (((((col) >> 6) ^ (row)) & 7) << 3))
#define PSWZ(r) ((((r) ^ ((r) >> 3)) & 3) << 3)

__device__ __forceinline__ void produce_half(u16* __restrict__ actbuf,
                                             const u16* __restrict__ ab,
                                             const short8v bw[2][2],
                                             int l15, int quad, int g) {
#pragma unroll
  for (int mt = 0; mt < 8; ++mt) {
    const u16* ar = ab + (mt * 16 + l15) * 64 + quad * 8;
    const short8v a0 = *reinterpret_cast<const short8v*>(ar);
    const short8v a1 = *reinterpret_cast<const short8v*>(ar + 32);
    f32x4 acc0 = {0.f, 0.f, 0.f, 0.f}, acc1 = {0.f, 0.f, 0.f, 0.f};
    acc0 = __builtin_amdgcn_mfma_f32_16x16x32_bf16(a0, bw[0][0], acc0, 0, 0, 0);
    acc0 = __builtin_amdgcn_mfma_f32_16x16x32_bf16(a1, bw[0][1], acc0, 0, 0, 0);
    acc1 = __builtin_amdgcn_mfma_f32_16x16x32_bf16(a0, bw[1][0], acc1, 0, 0, 0);
    acc1 = __builtin_amdgcn_mfma_f32_16x16x32_bf16(a1, bw[1][1], acc1, 0, 0, 0);
    const int qb = g * 128 + mt * 16 + quad * 4;      // LOCAL token col in [0,512)
    const int cs = ACT_SWZ(l15, qb);
    *reinterpret_cast<uint2*>(&actbuf[l15 * 512 + cs]) =
        make_uint2(pk_trunc(acc0[1], acc0[0]), pk_trunc(acc0[3], acc0[2]));
    if (l15 < 8)
      *reinterpret_cast<uint2*>(&actbuf[(16 + l15) * 512 + cs]) =
          make_uint2(pk_trunc(acc1[1], acc1[0]), pk_trunc(acc1[3], acc1[2]));
  }
}

__device__ __forceinline__ void consume_half(const u16* __restrict__ actbuf,
                                             const u16* __restrict__ planeTc,
                                             const u16* __restrict__ y2row,
                                             u16* __restrict__ outpc,
                                             float mw, int dpair, int cs2, int d, int h, int half) {
  __builtin_amdgcn_s_setprio(1);
  const int k = dpair * 2 + d;
  const int hc = half * 2 + cs2;
  const int colb = h * 16 + cs2 * 8;
  const int wst = dpair ? (24 - hc * 8) : (hc * 8);
  short8v vPr;
  if (d == 0) vPr = *reinterpret_cast<const short8v*>(y2row + h * 32 + wst);
  else        vPr = *reinterpret_cast<const short8v*>(planeTc + h * 40 + (wst ^ PSWZ(h)));
  short8v vPe;
  {
    const u32* s = (const u32*)&vPr;
    u32* dq = (u32*)&vPe;
    if (dpair) {
      dq[0] = (s[3] >> 16) | (s[3] << 16);
      dq[1] = (s[2] >> 16) | (s[2] << 16);
      dq[2] = (s[1] >> 16) | (s[1] << 16);
      dq[3] = (s[0] >> 16) | (s[0] << 16);
    } else {
      dq[0] = s[0]; dq[1] = s[1]; dq[2] = s[2]; dq[3] = s[3];
    }
  }
#define ACTP(row) (*reinterpret_cast<const short8v*>(&actbuf[(row) * 512 + ACT_SWZ((row), colb)]))
  const short8v vGl = ACTP(0 + k);
  const short8v vGm = ACTP(4 + k);
  const short8v vGr = ACTP(8 + k);
  const short8v vL  = ACTP(12 + k);
  const short8v vU  = ACTP(16 + k);
  const short8v vD  = ACTP(20 + k);
#undef ACTP
  const bool top = (h == 0), bot = (h == 31);
  float H = 0.f, prev = 0.f;
  u32 ox[4];
#pragma unroll
  for (int j = 0; j < 8; ++j) {
    float el = __expf(-ex8(vGl, j));
    const float em = __expf(-ex8(vGm, j));
    float er = __expf(-ex8(vGr, j));
    if (top) el = 1e30f;
    if (bot) er = 1e30f;
    const float pl2 = 1.f + el, pm = 1.f + em, pr = 1.f + er;
    const float ul = pm * pr, um = pl2 * pr, ur = pl2 * pm;
    const float rcpS = __builtin_amdgcn_rcpf(ul + um + ur);
    const float xv = ex8(vPe, j);
    const float Lx = ex8(vL, j) * xv;
    const float up = dpp_shr1(H);
    const float dn = dpp_shl1(H);
    H = fmaf(ul * rcpS, up, fmaf(um * rcpS, H, fmaf(ur * rcpS, dn, Lx)));
    float part = fmaf(H, ex8(vU, j), xv * ex8(vD, j)) * mw;
    part = xhalf_sum(part);
    if (j & 1) ox[j >> 1] = pk_trunc(part, prev);
    else prev = part;
  }
  if (d == 0) {
    uint4 o;
    o.x = ox[0]; o.y = ox[1]; o.z = ox[2]; o.w = ox[3];
    *reinterpret_cast<uint4*>(&outpc[h * 64 + dpair * 32 + ((hc * 8) ^ ((h & 3) << 3))]) = o;
  }
  __builtin_amdgcn_s_setprio(0);
}

__global__ __launch_bounds__(512, 4) void scan_k(const u16* __restrict__ y2b,
                                                 const u16* __restrict__ xpA,
                                                 const u16* __restrict__ wB,
                                                 const float* __restrict__ mwp,
                                                 u16* __restrict__ out1) {
  const int bc2 = blockIdx.x;            // 0..1535
  const int b = bc2 / 384;
  const int cpair = bc2 - b * 384;
  const int c0 = cpair * 2;
  __shared__ __align__(16) u16 actA[24 * 512];      // 24,576 B
  __shared__ __align__(16) u16 actB[24 * 512];      // 24,576 B
  __shared__ __align__(16) u16 planeT[2][1280];     //  5,120 B  [ch][w:32][h:40 swz]
  __shared__ __align__(16) u16 outp[2][32 * 64];    //  8,192 B  (total 62,464)
  const int t = threadIdx.x;
  const int wid = t >> 6, lane = t & 63, l15 = lane & 15, quad = lane >> 4;
  const int ch = wid >> 2;               // wave's channel (0/1)
  const int g = wid & 3;                 // producer index within group
  const int dpair = g & 1, cs2 = g >> 1;
  const int d = lane >> 5, h = lane & 31;
  const int c = c0 + ch;
  const int bc = b * DD + c;
  // ---- prologue: transposed planes for both channels ----
  {
    const int pch = t >> 8, idx = t & 255;
    const u16* yp = y2b + (size_t)(b * DD + c0 + pch) * PP;
#pragma unroll
    for (int i2 = 0; i2 < 2; ++i2) {
      const int i = idx + i2 * 256;
      const u32 v = reinterpret_cast<const u32*>(yp)[i];
      const int p0 = i * 2;
      const int hh = p0 >> 5, ww = p0 & 31;
      planeT[pch][ww * 40 + (hh ^ PSWZ(ww))] = (u16)v;
      planeT[pch][(ww + 1) * 40 + (hh ^ PSWZ(ww + 1))] = (u16)(v >> 16);
    }
  }
  // ---- per-channel projection weights ----
  const u16* wc = wB + (size_t)c * 2048;
  short8v bw[2][2];
#pragma unroll
  for (int nt = 0; nt < 2; ++nt)
#pragma unroll
    for (int ks = 0; ks < 2; ++ks)
      bw[nt][ks] = *reinterpret_cast<const short8v*>(wc + (nt * 16 + l15) * 64 + ks * 32 + quad * 8);
  const u16* xb = xpA + ((size_t)(b * 1024)) * 64;
  const u16* y2row = y2b + (size_t)bc * PP;
  const float mw = mwp[dpair * 2 + d];
  // ---- prologue produce: waves0-3 -> actA = c0 half0 ----
  if (ch == 0) produce_half(actA, xb + (size_t)(g * 128) * 64, bw, l15, quad, g);
  __syncthreads();   // BAR0: planes + actA(c0h0)
  // ---- R1 ----
  if (ch == 0) consume_half(actA, planeT[0], y2row, outp[0], mw, dpair, cs2, d, h, 0);
  else         produce_half(actB, xb + (size_t)(g * 128) * 64, bw, l15, quad, g);
  __syncthreads();   // BAR1
  // ---- R2 ----
  if (ch == 1) consume_half(actB, planeT[1], y2row, outp[1], mw, dpair, cs2, d, h, 0);
  else         produce_half(actA, xb + (size_t)(512 + g * 128) * 64, bw, l15, quad, g);
  __syncthreads();   // BAR2
  // ---- R3 ----
  if (ch == 0) consume_half(actA, planeT[0], y2row, outp[0], mw, dpair, cs2, d, h, 1);
  else         produce_half(actB, xb + (size_t)(512 + g * 128) * 64, bw, l15, quad, g);
  __syncthreads();   // BAR3
  // ---- R4 ----
  if (ch == 1) consume_half(actB, planeT[1], y2row, outp[1], mw, dpair, cs2, d, h, 1);
  __syncthreads();   // BAR4
  // ---- combine both channels, full-line coalesced stores ----
  const int hh2 = t >> 4, wp = t & 15;
  const int wsw = (wp * 2) ^ ((hh2 & 3) << 3);
#pragma unroll
  for (int cc = 0; cc < 2; ++cc) {
    const u32 u0 = *reinterpret_cast<const u32*>(&outp[cc][hh2 * 64 + wsw]);
    const u32 u1 = *reinterpret_cast<const u32*>(&outp[cc][hh2 * 64 + 32 + wsw]);
    const float v0 = b2f((u16)u0) + b2f((u16)u1);
    const float v1 = b2f((u16)(u0 >> 16)) + b2f((u16)(u1 >> 16));
    *reinterpret_cast<u32*>(out1 + (size_t)(b * DD + c0 + cc) * PP + hh2 * 32 + wp * 2) =
        pk_trunc(v1, v0);
  }
}

extern "C" void kernel_launch(void* const* d_in, const int* in_sizes, int n_in,
                              void* d_out, int out_size, void* d_ws, size_t ws_size,
                              hipStream_t stream) {
  const float* hs   = (const float*)d_in[0];
  const float* nw   = (const float*)d_in[1];
  const float* nb   = (const float*)d_in[2];
  const float* win  = (const float*)d_in[3];
  const float* c7w  = (const float*)d_in[4];
  const float* c7b  = (const float*)d_in[5];
  const float* xdw  = (const float*)d_in[6];
  const float* wupw = (const float*)d_in[7];
  const float* lupw = (const float*)d_in[8];
  const float* uupw = (const float*)d_in[9];
  const float* dcow = (const float*)d_in[10];
  const float* mww  = (const float*)d_in[11];
  const float* wout = (const float*)d_in[12];
  const float* odw  = (const float*)d_in[13];
  const float* wprj = (const float*)d_in[14];
  float* out0 = (float*)d_out;
  float* shortcut = out0 + (size_t)NTOK * DD;

  char* ws = (char*)d_ws;
  u16* lnA    = (u16*)(ws + 0);            // 6,291,456
  u16* wInB   = (u16*)(ws + 6291456);      // 1,179,648
  u16* wOutB  = (u16*)(ws + 7471104);      // 1,179,648
  u16* wPrjB  = (u16*)(ws + 8650752);      // 1,179,648
  u16* wB     = (u16*)(ws + 9830400);      // 3,145,728
  u16* wXdB   = (u16*)(ws + 12976128);     //    98,304
  u16* xpA    = (u16*)(ws + 13074432);     //   524,288
  u16* y1b    = (u16*)(ws + 13598720);     // 6,291,456  y1 (gemm1->dw7); later y3 (gemm2->dw3)
  u16* y2b    = (u16*)(ws + 19890176);     // 6,291,456  y2 (dw7 -> xdgemm+scan)
  u16* out1   = (u16*)(ws + 26181632);     // 6,291,456  scan->gemm2; later y4 (dw3->gemm3)
  u16* y3b    = y1b;
  u16* y4b    = out1;

  prep_ln_k<<<11968, 256, 0, stream>>>(hs, nw, nb, lnA, shortcut,
                                       win, wInB, wout, wOutB, wprj, wPrjB,
                                       xdw, wXdB, wupw, lupw, uupw, dcow, wB);
  gemm_nl<<<dim3(32, 12), 256, 0, stream>>>(wInB, lnA, y1b, 3);            // in_proj -> y1 (LDS-free)
  dwconv7_k<<<3072, 256, 0, stream>>>(y1b, c7w, c7b, y2b);                 // y2 bf16 ch-major
  xdgemm_k<<<256, 256, 0, stream>>>(wXdB, y2b, xpA);                       // xdown -> xpA (h-major rows)
  scan_k<<<1536, 512, 0, stream>>>(y2b, xpA, wB, mww, out1);               // out1 bf16 ch-major (P/C)
  gemm_cm<<<dim3(32, 12), 256, 0, stream>>>(wOutB, out1, y3b, 3);          // outconv -> y3 (A-direct)
  dwconv3_k<<<3072, 256, 0, stream>>>(y3b, odw, y4b);                      // dw3 + x*relu(x) -> y4 ch-major
  gemm_cm<<<dim3(32, 12), 256, 0, stream>>>(wPrjB, y4b, out0, 1);          // outproj -> out f32 (A-direct)
}

// Round 8
// 226.713 us; speedup vs baseline: 1.1129x; 1.1129x over previous
//
#include <hip/hip_runtime.h>

typedef unsigned short u16;
typedef unsigned int u32;
typedef __attribute__((ext_vector_type(8))) short short8v;   // 8 x bf16 (raw bits)
typedef __attribute__((ext_vector_type(4))) float f32x4;
typedef __attribute__((ext_vector_type(2))) unsigned u32x2v;

#define DD 768
#define PP 1024
#define NTOK 4096

__device__ __forceinline__ u16 f2bf(float f) {
  u32 u = __builtin_bit_cast(u32, f);
  u += 0x7fffu + ((u >> 16) & 1u);
  return (u16)(u >> 16);
}
__device__ __forceinline__ float b2f(u16 v) {
  return __builtin_bit_cast(float, (u32)v << 16);
}
// pack hi16(fa)<<16 | hi16(fb) in ONE v_perm_b32 (truncating bf16 pack)
__device__ __forceinline__ u32 pk_trunc(float fa, float fb) {
  return __builtin_amdgcn_perm(__builtin_bit_cast(u32, fa), __builtin_bit_cast(u32, fb), 0x07060302u);
}
// extract element j of a bf16x8 register as float (j MUST be compile-time after unroll)
__device__ __forceinline__ float ex8(const short8v& v, int j) {
  const u32 dw = ((const u32*)&v)[j >> 1];
  return __builtin_bit_cast(float, (j & 1) ? (dw & 0xffff0000u) : (dw << 16));
}
__device__ __forceinline__ float dpp_shr1(float x) {   // lane i <- i-1
  return __builtin_bit_cast(float,
      __builtin_amdgcn_update_dpp(0, __builtin_bit_cast(int, x), 0x138, 0xf, 0xf, true));
}
__device__ __forceinline__ float dpp_shl1(float x) {   // lane i <- i+1
  return __builtin_bit_cast(float,
      __builtin_amdgcn_update_dpp(0, __builtin_bit_cast(int, x), 0x130, 0xf, 0xf, true));
}
__device__ __forceinline__ float xhalf_sum(float p) {  // p(lane) + p(lane^32), VALU pipe
#if __has_builtin(__builtin_amdgcn_permlane32_swap)
  u32x2v sw = __builtin_amdgcn_permlane32_swap(__builtin_bit_cast(u32, p),
                                               __builtin_bit_cast(u32, p), false, false);
  return __builtin_bit_cast(float, sw[0]) + __builtin_bit_cast(float, sw[1]);
#else
  return p + __shfl_xor(p, 32, 64);
#endif
}

// ---------------- fused: LayerNorm+shortcut  AND  all weight prep (weight-convert vec x4) ------
__global__ __launch_bounds__(256) void prep_ln_k(const float* __restrict__ hs,
                                                 const float* __restrict__ gw, const float* __restrict__ gb,
                                                 u16* __restrict__ lnout, float* __restrict__ shortcut,
                                                 const float* __restrict__ win, u16* __restrict__ wInB,
                                                 const float* __restrict__ wout, u16* __restrict__ wOutB,
                                                 const float* __restrict__ wprj, u16* __restrict__ wPrjB,
                                                 const float* __restrict__ xdw, u16* __restrict__ wXdB,
                                                 const float* __restrict__ wup, const float* __restrict__ lup,
                                                 const float* __restrict__ uup, const float* __restrict__ dco,
                                                 u16* __restrict__ wB) {
  const int id = blockIdx.x;
  const int t = threadIdx.x;
  if (id < 4096) {                       // -------- LayerNorm on token id --------
    const int tok = id;
    const float* xr = hs + (size_t)tok * DD;
    float v0 = xr[t], v1 = xr[t + 256], v2 = xr[t + 512];
    float s = v0 + v1 + v2;
    float q = v0 * v0 + v1 * v1 + v2 * v2;
#pragma unroll
    for (int off = 32; off > 0; off >>= 1) {
      s += __shfl_down(s, off, 64);
      q += __shfl_down(q, off, 64);
    }
    __shared__ float ss[4], qs[4];
    const int wid = t >> 6, lane = t & 63;
    if (lane == 0) { ss[wid] = s; qs[wid] = q; }
    __syncthreads();
    const float st = ss[0] + ss[1] + ss[2] + ss[3];
    const float qt = qs[0] + qs[1] + qs[2] + qs[3];
    const float mu = st * (1.f / 768.f);
    const float var = qt * (1.f / 768.f) - mu * mu;
    const float rstd = rsqrtf(var + 1e-5f);
    float* sc = shortcut + (size_t)tok * DD;
    u16* lo = lnout + (size_t)tok * DD;
    sc[t] = v0; sc[t + 256] = v1; sc[t + 512] = v2;
    lo[t]       = f2bf((v0 - mu) * rstd * gw[t] + gb[t]);
    lo[t + 256] = f2bf((v1 - mu) * rstd * gw[t + 256] + gb[t + 256]);
    lo[t + 512] = f2bf((v2 - mu) * rstd * gw[t + 512] + gb[t + 512]);
    return;
  }
  const int id2 = id - 4096;
  if (id2 < 1728) {                      // -------- 3 x 589824 f32 -> bf16, x4 vectorized --------
    const int m = id2 / 576;
    const int i = (id2 - m * 576) * 1024 + t * 4;
    const float* s = (m == 0) ? win : (m == 1) ? wout : wprj;
    u16* d = (m == 0) ? wInB : (m == 1) ? wOutB : wPrjB;
    const float4 v = *reinterpret_cast<const float4*>(s + i);
    u16 o[4] = {f2bf(v.x), f2bf(v.y), f2bf(v.z), f2bf(v.w)};
    *reinterpret_cast<uint2*>(d + i) = *reinterpret_cast<const uint2*>(o);
  } else if (id2 < 1776) {               // -------- xdown 48x768 -> 64x768 padded, x4 --------
    const int i = (id2 - 1728) * 1024 + t * 4;     // rows of 768 are 4-divisible: no row straddle
    const int r = i / DD;
    if (r < 48) {
      const float4 v = *reinterpret_cast<const float4*>(xdw + i);
      u16 o[4] = {f2bf(v.x), f2bf(v.y), f2bf(v.z), f2bf(v.w)};
      *reinterpret_cast<uint2*>(wXdB + i) = *reinterpret_cast<const uint2*>(o);
    } else {
      *reinterpret_cast<uint2*>(wXdB + i) = make_uint2(0u, 0u);
    }
  } else {                               // -------- gather scan weights --------
    const int c = id2 - 1776;
    u16* dst = wB + (size_t)c * 2048;
    for (int i = t; i < 2048; i += 256) {
      const int row = i >> 6, s = i & 63;
      u16 v = 0;
      if (row < 24 && s < 48) {
        const int k = row & 3, type = row >> 2;
        const int ch = k * DD + c;
        const float* src;
        if (type < 3) src = wup + ((size_t)(type * 3072 + ch)) * 48;
        else if (type == 3) src = lup + (size_t)ch * 48;
        else if (type == 4) src = uup + (size_t)ch * 48;
        else src = dco + (size_t)ch * 48;
        v = f2bf(src[s]);
      }
      dst[i] = v;
    }
  }
}

// ---------------- bf16 MFMA GEMM (R6 best-measured): out[o,pg] = sum_c A[o,c]*B[pg,c] ----------
// BK=64 (12 iters) + register prefetch right after the LDS-ready barrier: next-tile global loads
// fly under the 12-ds_read+16-MFMA compute phase, so the vmcnt(0) barrier drain finds them done.
// BSRC 0: B token-major [pg][c].  BSRC 1: B channel-major [b][c][p] (LDS-transpose staging).
// mode 1: store f32 token-major out[pg*768 + o];  mode 3: store bf16 channel-major.
template <int BSRC>
__global__ __launch_bounds__(256) void gemm_bf16(const u16* __restrict__ A,
                                                 const u16* __restrict__ Bt,
                                                 void* __restrict__ outv, const int mode) {
  __shared__ u16 Al[64][72];      //  9,216 B
  __shared__ u16 BlF[144 * 72];   // 20,736 B  row-permuted: phys = tok + (tok>>3)
  const int t = threadIdx.x;
  const int ntile = blockIdx.x * 128;
  const int mtile = blockIdx.y * 64;
  const int bb = ntile >> 10, pq0 = ntile & 1023;
  const int wid = t >> 6, lane = t & 63;
  const int m0 = (wid & 1) * 32, n0 = (wid >> 1) * 64;
  const int l15 = lane & 15, quad = lane >> 4;
  f32x4 acc[2][4];
#pragma unroll
  for (int mi = 0; mi < 2; ++mi)
#pragma unroll
    for (int ni = 0; ni < 4; ++ni) acc[mi][ni] = (f32x4){0.f, 0.f, 0.f, 0.f};
  // staging ids
  const int ra = t >> 2, sa = t & 3;                                   // A: 4 thr/row, 16 el each
  const u16* ag = A + (size_t)(mtile + ra) * DD + sa * 16;
  const int rb = t >> 1, hb = t & 1;                                   // BSRC0: 2 thr/row, 32 el
  const u16* bg = Bt + (size_t)(ntile + rb) * DD + hb * 32;
  const int chp = t >> 4, tok0 = (t & 15) * 8;                         // BSRC1: pairs chp, chp+16
  const u16* bgc0 = Bt + ((size_t)(bb * DD + chp * 2)) * PP + pq0 + tok0;
  const u16* bgc1 = Bt + ((size_t)(bb * DD + (chp + 16) * 2)) * PP + pq0 + tok0;
  uint4 pa0, pa1, pb0, pb1, pb2, pb3;
#define LOADK(k0)                                                              \
  {                                                                            \
    pa0 = *reinterpret_cast<const uint4*>(ag + (k0));                          \
    pa1 = *reinterpret_cast<const uint4*>(ag + (k0) + 8);                      \
    if (BSRC == 0) {                                                           \
      pb0 = *reinterpret_cast<const uint4*>(bg + (k0));                        \
      pb1 = *reinterpret_cast<const uint4*>(bg + (k0) + 8);                    \
      pb2 = *reinterpret_cast<const uint4*>(bg + (k0) + 16);                   \
      pb3 = *reinterpret_cast<const uint4*>(bg + (k0) + 24);                   \
    } else {                                                                   \
      pb0 = *reinterpret_cast<const uint4*>(bgc0 + (size_t)(k0) * PP);         \
      pb1 = *reinterpret_cast<const uint4*>(bgc0 + (size_t)((k0) + 1) * PP);   \
      pb2 = *reinterpret_cast<const uint4*>(bgc1 + (size_t)(k0) * PP);         \
      pb3 = *reinterpret_cast<const uint4*>(bgc1 + (size_t)((k0) + 1) * PP);   \
    }                                                                          \
  }
  LOADK(0);
  for (int k0 = 0; k0 < DD; k0 += 64) {
    __syncthreads();                     // prev compute done reading LDS (prefetch already landed)
    *reinterpret_cast<uint4*>(&Al[ra][sa * 16]) = pa0;
    *reinterpret_cast<uint4*>(&Al[ra][sa * 16 + 8]) = pa1;
    if (BSRC == 0) {
      const int pr = rb + (rb >> 3);
      *reinterpret_cast<uint4*>(&BlF[pr * 72 + hb * 32]) = pb0;
      *reinterpret_cast<uint4*>(&BlF[pr * 72 + hb * 32 + 8]) = pb1;
      *reinterpret_cast<uint4*>(&BlF[pr * 72 + hb * 32 + 16]) = pb2;
      *reinterpret_cast<uint4*>(&BlF[pr * 72 + hb * 32 + 24]) = pb3;
    } else {
      union { uint4 v; u16 u[8]; } ua, ub, uc, ud;
      ua.v = pb0; ub.v = pb1; uc.v = pb2; ud.v = pb3;
#pragma unroll
      for (int i2 = 0; i2 < 8; ++i2) {
        const int prow = (tok0 + i2 + ((tok0 + i2) >> 3)) * 72;
        *reinterpret_cast<u32*>(&BlF[prow + chp * 2]) =
            (u32)ua.u[i2] | ((u32)ub.u[i2] << 16);
        *reinterpret_cast<u32*>(&BlF[prow + chp * 2 + 32]) =
            (u32)uc.u[i2] | ((u32)ud.u[i2] << 16);
      }
    }
    __syncthreads();                     // LDS ready
    if (k0 + 64 < DD) LOADK(k0 + 64);    // prefetch flies under compute below
    short8v af[2][2], bfr[4][2];
#pragma unroll
    for (int mi = 0; mi < 2; ++mi)
#pragma unroll
      for (int ks = 0; ks < 2; ++ks)
        af[mi][ks] = *reinterpret_cast<const short8v*>(&Al[m0 + mi * 16 + l15][ks * 32 + quad * 8]);
#pragma unroll
    for (int ni = 0; ni < 4; ++ni) {
      const int tl = n0 + ni * 16 + l15;
      const int prow = (tl + (tl >> 3)) * 72;
#pragma unroll
      for (int ks = 0; ks < 2; ++ks)
        bfr[ni][ks] = *reinterpret_cast<const short8v*>(&BlF[prow + ks * 32 + quad * 8]);
    }
#pragma unroll
    for (int mi = 0; mi < 2; ++mi)
#pragma unroll
      for (int ni = 0; ni < 4; ++ni) {
        acc[mi][ni] = __builtin_amdgcn_mfma_f32_16x16x32_bf16(af[mi][0], bfr[ni][0], acc[mi][ni], 0, 0, 0);
        acc[mi][ni] = __builtin_amdgcn_mfma_f32_16x16x32_bf16(af[mi][1], bfr[ni][1], acc[mi][ni], 0, 0, 0);
      }
  }
#undef LOADK
#pragma unroll
  for (int mi = 0; mi < 2; ++mi) {
#pragma unroll
    for (int ni = 0; ni < 4; ++ni) {
      const int ob = mtile + m0 + mi * 16 + quad * 4;
      const int pg = ntile + n0 + ni * 16 + l15;
      if (mode == 1) {
        *reinterpret_cast<f32x4*>((float*)outv + (size_t)pg * DD + ob) = acc[mi][ni];
      } else {
        const int pq = pg & 1023;
        u16* dstb = (u16*)outv;
#pragma unroll
        for (int r = 0; r < 4; ++r)
          dstb[((size_t)(bb * DD + ob + r)) * PP + pq] = f2bf(acc[mi][ni][r]);
      }
    }
  }
}

// ---------------- xdown GEMM with register prefetch ----------------
// grid 256: 16-token N-tiles. A = wXdB 64x768 (rows 48+ zero), i = ((p&31)>>4)*512 + (p>>5)*16 + (p&15)
__global__ __launch_bounds__(256) void xdgemm_k(const u16* __restrict__ A,
                                                const u16* __restrict__ Ycm,
                                                u16* __restrict__ xpA) {
  __shared__ u16 Al[64][72];
  __shared__ u16 Bl[16][72];
  const int t = threadIdx.x;
  const int ntile = blockIdx.x * 16;
  const int bb = ntile >> 10, pq0 = ntile & 1023;
  const int wid = t >> 6, lane = t & 63, l15 = lane & 15, quad = lane >> 4;
  f32x4 acc = (f32x4){0.f, 0.f, 0.f, 0.f};
  const int arow = t >> 2, aks = (t & 3) * 16;
  const u16* ag = A + (size_t)arow * DD + aks;
  const int chp = t >> 3;          // 0..31 channel-pairs (ch = 2*chp)
  const int tk0 = (t & 7) * 2;     // tokens tk0, tk0+1
  const u16* bg0 = Ycm + ((size_t)(bb * DD + chp * 2)) * PP + pq0 + tk0;
  uint4 pa0, pa1;
  u32 pb0, pb1;
#define LOADX(k0)                                                     \
  {                                                                   \
    pa0 = *reinterpret_cast<const uint4*>(ag + (k0));                 \
    pa1 = *reinterpret_cast<const uint4*>(ag + (k0) + 8);             \
    pb0 = *reinterpret_cast<const u32*>(bg0 + (size_t)(k0) * PP);     \
    pb1 = *reinterpret_cast<const u32*>(bg0 + (size_t)((k0) + 1) * PP); \
  }
  LOADX(0);
  for (int k0 = 0; k0 < DD; k0 += 64) {
    __syncthreads();                     // prev compute done reading LDS
    *reinterpret_cast<uint4*>(&Al[arow][aks]) = pa0;
    *reinterpret_cast<uint4*>(&Al[arow][aks + 8]) = pa1;
    *reinterpret_cast<u32*>(&Bl[tk0][chp * 2]) = (pb0 & 0xffffu) | (pb1 << 16);
    *reinterpret_cast<u32*>(&Bl[tk0 + 1][chp * 2]) = (pb0 >> 16) | (pb1 & 0xffff0000u);
    __syncthreads();                     // LDS ready
    if (k0 + 64 < DD) LOADX(k0 + 64);    // prefetch flies under compute
#pragma unroll
    for (int ks = 0; ks < 2; ++ks) {
      const short8v af = *reinterpret_cast<const short8v*>(&Al[wid * 16 + l15][ks * 32 + quad * 8]);
      const short8v bf = *reinterpret_cast<const short8v*>(&Bl[l15][ks * 32 + quad * 8]);
      acc = __builtin_amdgcn_mfma_f32_16x16x32_bf16(af, bf, acc, 0, 0, 0);
    }
  }
#undef LOADX
  const int pq = pq0 + l15;
  const int i = ((pq & 31) >> 4) * 512 + (pq >> 5) * 16 + (pq & 15);
  u16* dst = xpA + ((size_t)(bb * 1024 + i)) * 64 + wid * 16 + quad * 4;
  *reinterpret_cast<uint2*>(dst) = make_uint2(pk_trunc(acc[1], acc[0]), pk_trunc(acc[3], acc[2]));
}

// ---------------- depthwise 7x7 + bias, bf16 -> bf16 ----------------
__global__ __launch_bounds__(256) void dwconv7_k(const u16* __restrict__ x,
                                                 const float* __restrict__ wgt,
                                                 const float* __restrict__ bias,
                                                 u16* __restrict__ y) {
  const int bc = blockIdx.x;
  const int c = bc % DD;
  __shared__ float tile[38 * 38];
  __shared__ float wl[49];
  __shared__ float bsh[1];
  const int t = threadIdx.x;
  for (int i = t; i < 38 * 38; i += 256) tile[i] = 0.f;
  __syncthreads();
  const u16* xr = x + (size_t)bc * PP;
  for (int i = t; i < 512; i += 256) {
    const u32 v = reinterpret_cast<const u32*>(xr)[i];
    const int p0 = i * 2;
    const int h = p0 >> 5, w = p0 & 31;
    tile[(h + 3) * 38 + w + 3] = b2f((u16)v);
    tile[(h + 3) * 38 + w + 4] = b2f((u16)(v >> 16));
  }
  if (t < 49) wl[t] = wgt[c * 49 + t];
  if (t == 0) bsh[0] = bias[c];
  __syncthreads();
  u16* yo = y + (size_t)bc * PP;
  const int w = t & 31, hb = t >> 5;         // hb 0..7 -> rows hb*4 .. hb*4+3
  const float bv = bsh[0];
  float a0 = bv, a1 = bv, a2 = bv, a3 = bv;
#pragma unroll
  for (int rr = 0; rr < 10; ++rr) {          // input rows hb*4+rr
    float row[7];
#pragma unroll
    for (int kw = 0; kw < 7; ++kw) row[kw] = tile[(hb * 4 + rr) * 38 + w + kw];
    if (rr < 7) {
#pragma unroll
      for (int kw = 0; kw < 7; ++kw) a0 = fmaf(wl[rr * 7 + kw], row[kw], a0);
    }
    if (rr >= 1 && rr < 8) {
#pragma unroll
      for (int kw = 0; kw < 7; ++kw) a1 = fmaf(wl[(rr - 1) * 7 + kw], row[kw], a1);
    }
    if (rr >= 2 && rr < 9) {
#pragma unroll
      for (int kw = 0; kw < 7; ++kw) a2 = fmaf(wl[(rr - 2) * 7 + kw], row[kw], a2);
    }
    if (rr >= 3) {
#pragma unroll
      for (int kw = 0; kw < 7; ++kw) a3 = fmaf(wl[(rr - 3) * 7 + kw], row[kw], a3);
    }
  }
  yo[(hb * 4 + 0) * 32 + w] = f2bf(a0);
  yo[(hb * 4 + 1) * 32 + w] = f2bf(a1);
  yo[(hb * 4 + 2) * 32 + w] = f2bf(a2);
  yo[(hb * 4 + 3) * 32 + w] = f2bf(a3);
}

// ---------------- depthwise 3x3 (no bias) + x*relu(x), bf16 -> bf16 ----------------
__global__ __launch_bounds__(256) void dwconv3_k(const u16* __restrict__ x,
                                                 const float* __restrict__ wgt,
                                                 u16* __restrict__ y) {
  const int bc = blockIdx.x;
  const int c = bc % DD;
  __shared__ float tile[34 * 34];
  __shared__ float wl[9];
  const int t = threadIdx.x;
  for (int i = t; i < 34 * 34; i += 256) tile[i] = 0.f;
  __syncthreads();
  const u16* xr = x + (size_t)bc * PP;
  for (int i = t; i < 512; i += 256) {
    const u32 v = reinterpret_cast<const u32*>(xr)[i];
    const int p0 = i * 2;
    const int h = p0 >> 5, w = p0 & 31;
    tile[(h + 1) * 34 + w + 1] = b2f((u16)v);
    tile[(h + 1) * 34 + w + 2] = b2f((u16)(v >> 16));
  }
  if (t < 9) wl[t] = wgt[c * 9 + t];
  __syncthreads();
  u16* yo = y + (size_t)bc * PP;
  const int w = t & 31, hb = t >> 5;
  float a0 = 0.f, a1 = 0.f, a2 = 0.f, a3 = 0.f;
#pragma unroll
  for (int rr = 0; rr < 6; ++rr) {
    float row[3];
#pragma unroll
    for (int kw = 0; kw < 3; ++kw) row[kw] = tile[(hb * 4 + rr) * 34 + w + kw];
    if (rr < 3) {
#pragma unroll
      for (int kw = 0; kw < 3; ++kw) a0 = fmaf(wl[rr * 3 + kw], row[kw], a0);
    }
    if (rr >= 1 && rr < 4) {
#pragma unroll
      for (int kw = 0; kw < 3; ++kw) a1 = fmaf(wl[(rr - 1) * 3 + kw], row[kw], a1);
    }
    if (rr >= 2 && rr < 5) {
#pragma unroll
      for (int kw = 0; kw < 3; ++kw) a2 = fmaf(wl[(rr - 2) * 3 + kw], row[kw], a2);
    }
    if (rr >= 3) {
#pragma unroll
      for (int kw = 0; kw < 3; ++kw) a3 = fmaf(wl[(rr - 3) * 3 + kw], row[kw], a3);
    }
  }
  const float r0 = a0 > 0.f ? a0 * a0 : 0.f;
  const float r1 = a1 > 0.f ? a1 * a1 : 0.f;
  const float r2 = a2 > 0.f ? a2 * a2 : 0.f;
  const float r3 = a3 > 0.f ? a3 * a3 : 0.f;
  yo[(hb * 4 + 0) * 32 + w] = f2bf(r0);
  yo[(hb * 4 + 1) * 32 + w] = f2bf(r1);
  yo[(hb * 4 + 2) * 32 + w] = f2bf(r2);
  yo[(hb * 4 + 3) * 32 + w] = f2bf(r3);
}

// ---------------- producer/consumer fused scan (R6 structure, unchanged) ----------------
#define ACT_SWZ(row, col) ((col) ^ (((((col) >> 6) ^ (row)) & 7) << 3))
#define PSWZ(r) ((((r) ^ ((r) >> 3)) & 3) << 3)

__device__ __forceinline__ void produce_half(u16* __restrict__ actbuf,
                                             const u16* __restrict__ ab,
                                             const short8v bw[2][2],
                                             int l15, int quad, int g) {
#pragma unroll
  for (int mt = 0; mt < 8; ++mt) {
    const u16* ar = ab + (mt * 16 + l15) * 64 + quad * 8;
    const short8v a0 = *reinterpret_cast<const short8v*>(ar);
    const short8v a1 = *reinterpret_cast<const short8v*>(ar + 32);
    f32x4 acc0 = {0.f, 0.f, 0.f, 0.f}, acc1 = {0.f, 0.f, 0.f, 0.f};
    acc0 = __builtin_amdgcn_mfma_f32_16x16x32_bf16(a0, bw[0][0], acc0, 0, 0, 0);
    acc0 = __builtin_amdgcn_mfma_f32_16x16x32_bf16(a1, bw[0][1], acc0, 0, 0, 0);
    acc1 = __builtin_amdgcn_mfma_f32_16x16x32_bf16(a0, bw[1][0], acc1, 0, 0, 0);
    acc1 = __builtin_amdgcn_mfma_f32_16x16x32_bf16(a1, bw[1][1], acc1, 0, 0, 0);
    const int qb = g * 128 + mt * 16 + quad * 4;      // LOCAL token col in [0,512)
    const int cs = ACT_SWZ(l15, qb);
    *reinterpret_cast<uint2*>(&actbuf[l15 * 512 + cs]) =
        make_uint2(pk_trunc(acc0[1], acc0[0]), pk_trunc(acc0[3], acc0[2]));
    if (l15 < 8)
      *reinterpret_cast<uint2*>(&actbuf[(16 + l15) * 512 + cs]) =
          make_uint2(pk_trunc(acc1[1], acc1[0]), pk_trunc(acc1[3], acc1[2]));
  }
}

__device__ __forceinline__ void consume_half(const u16* __restrict__ actbuf,
                                             const u16* __restrict__ planeTc,
                                             const u16* __restrict__ y2row,
                                             u16* __restrict__ outpc,
                                             float mw, int dpair, int cs2, int d, int h, int half) {
  __builtin_amdgcn_s_setprio(1);
  const int k = dpair * 2 + d;
  const int hc = half * 2 + cs2;
  const int colb = h * 16 + cs2 * 8;
  const int wst = dpair ? (24 - hc * 8) : (hc * 8);
  short8v vPr;
  if (d == 0) vPr = *reinterpret_cast<const short8v*>(y2row + h * 32 + wst);
  else        vPr = *reinterpret_cast<const short8v*>(planeTc + h * 40 + (wst ^ PSWZ(h)));
  short8v vPe;
  {
    const u32* s = (const u32*)&vPr;
    u32* dq = (u32*)&vPe;
    if (dpair) {
      dq[0] = (s[3] >> 16) | (s[3] << 16);
      dq[1] = (s[2] >> 16) | (s[2] << 16);
      dq[2] = (s[1] >> 16) | (s[1] << 16);
      dq[3] = (s[0] >> 16) | (s[0] << 16);
    } else {
      dq[0] = s[0]; dq[1] = s[1]; dq[2] = s[2]; dq[3] = s[3];
    }
  }
#define ACTP(row) (*reinterpret_cast<const short8v*>(&actbuf[(row) * 512 + ACT_SWZ((row), colb)]))
  const short8v vGl = ACTP(0 + k);
  const short8v vGm = ACTP(4 + k);
  const short8v vGr = ACTP(8 + k);
  const short8v vL  = ACTP(12 + k);
  const short8v vU  = ACTP(16 + k);
  const short8v vD  = ACTP(20 + k);
#undef ACTP
  const bool top = (h == 0), bot = (h == 31);
  float H = 0.f, prev = 0.f;
  u32 ox[4];
#pragma unroll
  for (int j = 0; j < 8; ++j) {
    float el = __expf(-ex8(vGl, j));
    const float em = __expf(-ex8(vGm, j));
    float er = __expf(-ex8(vGr, j));
    if (top) el = 1e30f;
    if (bot) er = 1e30f;
    const float pl2 = 1.f + el, pm = 1.f + em, pr = 1.f + er;
    const float ul = pm * pr, um = pl2 * pr, ur = pl2 * pm;
    const float rcpS = __builtin_amdgcn_rcpf(ul + um + ur);
    const float xv = ex8(vPe, j);
    const float Lx = ex8(vL, j) * xv;
    const float up = dpp_shr1(H);
    const float dn = dpp_shl1(H);
    H = fmaf(ul * rcpS, up, fmaf(um * rcpS, H, fmaf(ur * rcpS, dn, Lx)));
    float part = fmaf(H, ex8(vU, j), xv * ex8(vD, j)) * mw;
    part = xhalf_sum(part);
    if (j & 1) ox[j >> 1] = pk_trunc(part, prev);
    else prev = part;
  }
  if (d == 0) {
    uint4 o;
    o.x = ox[0]; o.y = ox[1]; o.z = ox[2]; o.w = ox[3];
    *reinterpret_cast<uint4*>(&outpc[h * 64 + dpair * 32 + ((hc * 8) ^ ((h & 3) << 3))]) = o;
  }
  __builtin_amdgcn_s_setprio(0);
}

__global__ __launch_bounds__(512, 4) void scan_k(const u16* __restrict__ y2b,
                                                 const u16* __restrict__ xpA,
                                                 const u16* __restrict__ wB,
                                                 const float* __restrict__ mwp,
                                                 u16* __restrict__ out1) {
  const int bc2 = blockIdx.x;            // 0..1535
  const int b = bc2 / 384;
  const int cpair = bc2 - b * 384;
  const int c0 = cpair * 2;
  __shared__ __align__(16) u16 actA[24 * 512];      // 24,576 B
  __shared__ __align__(16) u16 actB[24 * 512];      // 24,576 B
  __shared__ __align__(16) u16 planeT[2][1280];     //  5,120 B  [ch][w:32][h:40 swz]
  __shared__ __align__(16) u16 outp[2][32 * 64];    //  8,192 B  (total 62,464)
  const int t = threadIdx.x;
  const int wid = t >> 6, lane = t & 63, l15 = lane & 15, quad = lane >> 4;
  const int ch = wid >> 2;               // wave's channel (0/1)
  const int g = wid & 3;                 // producer index within group
  const int dpair = g & 1, cs2 = g >> 1;
  const int d = lane >> 5, h = lane & 31;
  const int c = c0 + ch;
  const int bc = b * DD + c;
  // ---- prologue: transposed planes for both channels ----
  {
    const int pch = t >> 8, idx = t & 255;
    const u16* yp = y2b + (size_t)(b * DD + c0 + pch) * PP;
#pragma unroll
    for (int i2 = 0; i2 < 2; ++i2) {
      const int i = idx + i2 * 256;
      const u32 v = reinterpret_cast<const u32*>(yp)[i];
      const int p0 = i * 2;
      const int hh = p0 >> 5, ww = p0 & 31;
      planeT[pch][ww * 40 + (hh ^ PSWZ(ww))] = (u16)v;
      planeT[pch][(ww + 1) * 40 + (hh ^ PSWZ(ww + 1))] = (u16)(v >> 16);
    }
  }
  // ---- per-channel projection weights ----
  const u16* wc = wB + (size_t)c * 2048;
  short8v bw[2][2];
#pragma unroll
  for (int nt = 0; nt < 2; ++nt)
#pragma unroll
    for (int ks = 0; ks < 2; ++ks)
      bw[nt][ks] = *reinterpret_cast<const short8v*>(wc + (nt * 16 + l15) * 64 + ks * 32 + quad * 8);
  const u16* xb = xpA + ((size_t)(b * 1024)) * 64;
  const u16* y2row = y2b + (size_t)bc * PP;
  const float mw = mwp[dpair * 2 + d];
  // ---- prologue produce: waves0-3 -> actA = c0 half0 ----
  if (ch == 0) produce_half(actA, xb + (size_t)(g * 128) * 64, bw, l15, quad, g);
  __syncthreads();   // BAR0: planes + actA(c0h0)
  // ---- R1 ----
  if (ch == 0) consume_half(actA, planeT[0], y2row, outp[0], mw, dpair, cs2, d, h, 0);
  else         produce_half(actB, xb + (size_t)(g * 128) * 64, bw, l15, quad, g);
  __syncthreads();   // BAR1
  // ---- R2 ----
  if (ch == 1) consume_half(actB, planeT[1], y2row, outp[1], mw, dpair, cs2, d, h, 0);
  else         produce_half(actA, xb + (size_t)(512 + g * 128) * 64, bw, l15, quad, g);
  __syncthreads();   // BAR2
  // ---- R3 ----
  if (ch == 0) consume_half(actA, planeT[0], y2row, outp[0], mw, dpair, cs2, d, h, 1);
  else         produce_half(actB, xb + (size_t)(512 + g * 128) * 64, bw, l15, quad, g);
  __syncthreads();   // BAR3
  // ---- R4 ----
  if (ch == 1) consume_half(actB, planeT[1], y2row, outp[1], mw, dpair, cs2, d, h, 1);
  __syncthreads();   // BAR4
  // ---- combine both channels, full-line coalesced stores ----
  const int hh2 = t >> 4, wp = t & 15;
  const int wsw = (wp * 2) ^ ((hh2 & 3) << 3);
#pragma unroll
  for (int cc = 0; cc < 2; ++cc) {
    const u32 u0 = *reinterpret_cast<const u32*>(&outp[cc][hh2 * 64 + wsw]);
    const u32 u1 = *reinterpret_cast<const u32*>(&outp[cc][hh2 * 64 + 32 + wsw]);
    const float v0 = b2f((u16)u0) + b2f((u16)u1);
    const float v1 = b2f((u16)(u0 >> 16)) + b2f((u16)(u1 >> 16));
    *reinterpret_cast<u32*>(out1 + (size_t)(b * DD + c0 + cc) * PP + hh2 * 32 + wp * 2) =
        pk_trunc(v1, v0);
  }
}

extern "C" void kernel_launch(void* const* d_in, const int* in_sizes, int n_in,
                              void* d_out, int out_size, void* d_ws, size_t ws_size,
                              hipStream_t stream) {
  const float* hs   = (const float*)d_in[0];
  const float* nw   = (const float*)d_in[1];
  const float* nb   = (const float*)d_in[2];
  const float* win  = (const float*)d_in[3];
  const float* c7w  = (const float*)d_in[4];
  const float* c7b  = (const float*)d_in[5];
  const float* xdw  = (const float*)d_in[6];
  const float* wupw = (const float*)d_in[7];
  const float* lupw = (const float*)d_in[8];
  const float* uupw = (const float*)d_in[9];
  const float* dcow = (const float*)d_in[10];
  const float* mww  = (const float*)d_in[11];
  const float* wout = (const float*)d_in[12];
  const float* odw  = (const float*)d_in[13];
  const float* wprj = (const float*)d_in[14];
  float* out0 = (float*)d_out;
  float* shortcut = out0 + (size_t)NTOK * DD;

  char* ws = (char*)d_ws;
  u16* lnA    = (u16*)(ws + 0);            // 6,291,456
  u16* wInB   = (u16*)(ws + 6291456);      // 1,179,648
  u16* wOutB  = (u16*)(ws + 7471104);      // 1,179,648
  u16* wPrjB  = (u16*)(ws + 8650752);      // 1,179,648
  u16* wB     = (u16*)(ws + 9830400);      // 3,145,728
  u16* wXdB   = (u16*)(ws + 12976128);     //    98,304
  u16* xpA    = (u16*)(ws + 13074432);     //   524,288
  u16* y1b    = (u16*)(ws + 13598720);     // 6,291,456  y1 (gemm1->dw7); later y3 (gemm2->dw3)
  u16* y2b    = (u16*)(ws + 19890176);     // 6,291,456  y2 (dw7 -> xdgemm+scan)
  u16* out1   = (u16*)(ws + 26181632);     // 6,291,456  scan->gemm2; later y4 (dw3->gemm3)
  u16* y3b    = y1b;
  u16* y4b    = out1;

  prep_ln_k<<<6640, 256, 0, stream>>>(hs, nw, nb, lnA, shortcut,
                                      win, wInB, wout, wOutB, wprj, wPrjB,
                                      xdw, wXdB, wupw, lupw, uupw, dcow, wB);
  gemm_bf16<0><<<dim3(32, 12), 256, 0, stream>>>(wInB, lnA, y1b, 3);       // in_proj -> y1 bf16 ch-major
  dwconv7_k<<<3072, 256, 0, stream>>>(y1b, c7w, c7b, y2b);                 // y2 bf16 ch-major
  xdgemm_k<<<256, 256, 0, stream>>>(wXdB, y2b, xpA);                       // xdown -> xpA (h-major rows)
  scan_k<<<1536, 512, 0, stream>>>(y2b, xpA, wB, mww, out1);               // out1 bf16 ch-major (P/C)
  gemm_bf16<1><<<dim3(32, 12), 256, 0, stream>>>(wOutB, out1, y3b, 3);     // outconv -> y3 bf16 ch-major
  dwconv3_k<<<3072, 256, 0, stream>>>(y3b, odw, y4b);                      // dw3 + x*relu(x) -> y4 ch-major
  gemm_bf16<1><<<dim3(32, 12), 256, 0, stream>>>(wPrjB, y4b, out0, 1);     // outproj -> out f32 [b][t][d]
}

// Round 9
// 219.984 us; speedup vs baseline: 1.1470x; 1.0306x over previous
//
#include <hip/hip_runtime.h>

typedef unsigned short u16;
typedef unsigned int u32;
typedef __attribute__((ext_vector_type(8))) short short8v;   // 8 x bf16 (raw bits)
typedef __attribute__((ext_vector_type(4))) float f32x4;
typedef __attribute__((ext_vector_type(2))) unsigned u32x2v;

#define DD 768
#define PP 1024
#define NTOK 4096

__device__ __forceinline__ u16 f2bf(float f) {
  u32 u = __builtin_bit_cast(u32, f);
  u += 0x7fffu + ((u >> 16) & 1u);
  return (u16)(u >> 16);
}
__device__ __forceinline__ float b2f(u16 v) {
  return __builtin_bit_cast(float, (u32)v << 16);
}
// pack hi16(fa)<<16 | hi16(fb) in ONE v_perm_b32 (truncating bf16 pack)
__device__ __forceinline__ u32 pk_trunc(float fa, float fb) {
  return __builtin_amdgcn_perm(__builtin_bit_cast(u32, fa), __builtin_bit_cast(u32, fb), 0x07060302u);
}
// extract element j of a bf16x8 register as float (j MUST be compile-time after unroll)
__device__ __forceinline__ float ex8(const short8v& v, int j) {
  const u32 dw = ((const u32*)&v)[j >> 1];
  return __builtin_bit_cast(float, (j & 1) ? (dw & 0xffff0000u) : (dw << 16));
}
__device__ __forceinline__ float dpp_shr1(float x) {   // lane i <- i-1
  return __builtin_bit_cast(float,
      __builtin_amdgcn_update_dpp(0, __builtin_bit_cast(int, x), 0x138, 0xf, 0xf, true));
}
__device__ __forceinline__ float dpp_shl1(float x) {   // lane i <- i+1
  return __builtin_bit_cast(float,
      __builtin_amdgcn_update_dpp(0, __builtin_bit_cast(int, x), 0x130, 0xf, 0xf, true));
}
__device__ __forceinline__ float xhalf_sum(float p) {  // p(lane) + p(lane^32), VALU pipe
#if __has_builtin(__builtin_amdgcn_permlane32_swap)
  u32x2v sw = __builtin_amdgcn_permlane32_swap(__builtin_bit_cast(u32, p),
                                               __builtin_bit_cast(u32, p), false, false);
  return __builtin_bit_cast(float, sw[0]) + __builtin_bit_cast(float, sw[1]);
#else
  return p + __shfl_xor(p, 32, 64);
#endif
}

// ---------------- fused: LayerNorm+shortcut  AND  all weight prep (weight-convert vec x4) ------
__global__ __launch_bounds__(256) void prep_ln_k(const float* __restrict__ hs,
                                                 const float* __restrict__ gw, const float* __restrict__ gb,
                                                 u16* __restrict__ lnout, float* __restrict__ shortcut,
                                                 const float* __restrict__ win, u16* __restrict__ wInB,
                                                 const float* __restrict__ wout, u16* __restrict__ wOutB,
                                                 const float* __restrict__ wprj, u16* __restrict__ wPrjB,
                                                 const float* __restrict__ xdw, u16* __restrict__ wXdB,
                                                 const float* __restrict__ wup, const float* __restrict__ lup,
                                                 const float* __restrict__ uup, const float* __restrict__ dco,
                                                 u16* __restrict__ wB) {
  const int id = blockIdx.x;
  const int t = threadIdx.x;
  if (id < 4096) {                       // -------- LayerNorm on token id --------
    const int tok = id;
    const float* xr = hs + (size_t)tok * DD;
    float v0 = xr[t], v1 = xr[t + 256], v2 = xr[t + 512];
    float s = v0 + v1 + v2;
    float q = v0 * v0 + v1 * v1 + v2 * v2;
#pragma unroll
    for (int off = 32; off > 0; off >>= 1) {
      s += __shfl_down(s, off, 64);
      q += __shfl_down(q, off, 64);
    }
    __shared__ float ss[4], qs[4];
    const int wid = t >> 6, lane = t & 63;
    if (lane == 0) { ss[wid] = s; qs[wid] = q; }
    __syncthreads();
    const float st = ss[0] + ss[1] + ss[2] + ss[3];
    const float qt = qs[0] + qs[1] + qs[2] + qs[3];
    const float mu = st * (1.f / 768.f);
    const float var = qt * (1.f / 768.f) - mu * mu;
    const float rstd = rsqrtf(var + 1e-5f);
    float* sc = shortcut + (size_t)tok * DD;
    u16* lo = lnout + (size_t)tok * DD;
    sc[t] = v0; sc[t + 256] = v1; sc[t + 512] = v2;
    lo[t]       = f2bf((v0 - mu) * rstd * gw[t] + gb[t]);
    lo[t + 256] = f2bf((v1 - mu) * rstd * gw[t + 256] + gb[t + 256]);
    lo[t + 512] = f2bf((v2 - mu) * rstd * gw[t + 512] + gb[t + 512]);
    return;
  }
  const int id2 = id - 4096;
  if (id2 < 1728) {                      // -------- 3 x 589824 f32 -> bf16, x4 vectorized --------
    const int m = id2 / 576;
    const int i = (id2 - m * 576) * 1024 + t * 4;
    const float* s = (m == 0) ? win : (m == 1) ? wout : wprj;
    u16* d = (m == 0) ? wInB : (m == 1) ? wOutB : wPrjB;
    const float4 v = *reinterpret_cast<const float4*>(s + i);
    u16 o[4] = {f2bf(v.x), f2bf(v.y), f2bf(v.z), f2bf(v.w)};
    *reinterpret_cast<uint2*>(d + i) = *reinterpret_cast<const uint2*>(o);
  } else if (id2 < 1776) {               // -------- xdown 48x768 -> 64x768 padded, x4 --------
    const int i = (id2 - 1728) * 1024 + t * 4;     // rows of 768 are 4-divisible: no row straddle
    const int r = i / DD;
    if (r < 48) {
      const float4 v = *reinterpret_cast<const float4*>(xdw + i);
      u16 o[4] = {f2bf(v.x), f2bf(v.y), f2bf(v.z), f2bf(v.w)};
      *reinterpret_cast<uint2*>(wXdB + i) = *reinterpret_cast<const uint2*>(o);
    } else {
      *reinterpret_cast<uint2*>(wXdB + i) = make_uint2(0u, 0u);
    }
  } else {                               // -------- gather scan weights --------
    const int c = id2 - 1776;
    u16* dst = wB + (size_t)c * 2048;
    for (int i = t; i < 2048; i += 256) {
      const int row = i >> 6, s = i & 63;
      u16 v = 0;
      if (row < 24 && s < 48) {
        const int k = row & 3, type = row >> 2;
        const int ch = k * DD + c;
        const float* src;
        if (type < 3) src = wup + ((size_t)(type * 3072 + ch)) * 48;
        else if (type == 3) src = lup + (size_t)ch * 48;
        else if (type == 4) src = uup + (size_t)ch * 48;
        else src = dco + (size_t)ch * 48;
        v = f2bf(src[s]);
      }
      dst[i] = v;
    }
  }
}

// ---------------- bf16 MFMA GEMM, 64x64 tiles (balanced grid 768 = 3 blocks/CU) ----------------
// BK=64 + register prefetch after the LDS-ready barrier (R6-proven schedule). 8 blocks/CU LDS cap
// -> deep cross-block overlap replaces intra-block pipelining. Mode-3 epilogue staged through LDS:
// 2 coalesced uint4 stores/thread (128B lines) instead of 32 scalar u16 stores.
// BSRC 0: B token-major [pg][c].  BSRC 1: B channel-major [b][c][p] (LDS-transpose staging).
// mode 1: store f32 token-major out[pg*768 + o];  mode 3: store bf16 channel-major.
template <int BSRC>
__global__ __launch_bounds__(256) void gemm_bf16(const u16* __restrict__ A,
                                                 const u16* __restrict__ Bt,
                                                 void* __restrict__ outv, const int mode) {
  __shared__ u16 Al[64][72];      //  9,216 B
  __shared__ u16 BlF[71 * 72];    // 10,224 B  row-permuted: phys = tok + (tok>>3); reused as epilogue tile
  const int t = threadIdx.x;
  const int ntile = blockIdx.x * 64;
  const int mtile = blockIdx.y * 64;
  const int bb = ntile >> 10, pq0 = ntile & 1023;
  const int wid = t >> 6, lane = t & 63;
  const int m0 = (wid & 1) * 32, n0 = (wid >> 1) * 32;
  const int l15 = lane & 15, quad = lane >> 4;
  f32x4 acc[2][2];
#pragma unroll
  for (int mi = 0; mi < 2; ++mi)
#pragma unroll
    for (int ni = 0; ni < 2; ++ni) acc[mi][ni] = (f32x4){0.f, 0.f, 0.f, 0.f};
  // staging ids
  const int ra = t >> 2, sa = t & 3;                                   // A: 4 thr/row, 16 el each
  const u16* ag = A + (size_t)(mtile + ra) * DD + sa * 16;
  const int rb = t >> 2, hb = t & 3;                                   // BSRC0: 4 thr/row, 16 el
  const u16* bg = Bt + (size_t)(ntile + rb) * DD + hb * 16;
  const int chp = t >> 3, tok0 = (t & 7) * 8;                          // BSRC1: ch pair 2chp, 8 toks
  const u16* bgc0 = Bt + ((size_t)(bb * DD + chp * 2)) * PP + pq0 + tok0;
  const u16* bgc1 = bgc0 + PP;                                         // channel 2chp+1
  uint4 pa0, pa1, pb0, pb1;
#define LOADK(k0)                                                              \
  {                                                                            \
    pa0 = *reinterpret_cast<const uint4*>(ag + (k0));                          \
    pa1 = *reinterpret_cast<const uint4*>(ag + (k0) + 8);                      \
    if (BSRC == 0) {                                                           \
      pb0 = *reinterpret_cast<const uint4*>(bg + (k0));                        \
      pb1 = *reinterpret_cast<const uint4*>(bg + (k0) + 8);                    \
    } else {                                                                   \
      pb0 = *reinterpret_cast<const uint4*>(bgc0 + (size_t)(k0) * PP);         \
      pb1 = *reinterpret_cast<const uint4*>(bgc1 + (size_t)(k0) * PP);         \
    }                                                                          \
  }
  LOADK(0);
  for (int k0 = 0; k0 < DD; k0 += 64) {
    __syncthreads();                     // prev compute done reading LDS (prefetch already landed)
    *reinterpret_cast<uint4*>(&Al[ra][sa * 16]) = pa0;
    *reinterpret_cast<uint4*>(&Al[ra][sa * 16 + 8]) = pa1;
    if (BSRC == 0) {
      const int pr = rb + (rb >> 3);
      *reinterpret_cast<uint4*>(&BlF[pr * 72 + hb * 16]) = pb0;
      *reinterpret_cast<uint4*>(&BlF[pr * 72 + hb * 16 + 8]) = pb1;
    } else {
      union { uint4 v; u16 u[8]; } ua, ub;
      ua.v = pb0; ub.v = pb1;
#pragma unroll
      for (int i2 = 0; i2 < 8; ++i2) {
        const int tk = tok0 + i2;
        const int prow = (tk + (tk >> 3)) * 72;
        *reinterpret_cast<u32*>(&BlF[prow + chp * 2]) =
            (u32)ua.u[i2] | ((u32)ub.u[i2] << 16);
      }
    }
    __syncthreads();                     // LDS ready
    if (k0 + 64 < DD) LOADK(k0 + 64);    // prefetch flies under compute below
    short8v af[2][2], bfr[2][2];
#pragma unroll
    for (int mi = 0; mi < 2; ++mi)
#pragma unroll
      for (int ks = 0; ks < 2; ++ks)
        af[mi][ks] = *reinterpret_cast<const short8v*>(&Al[m0 + mi * 16 + l15][ks * 32 + quad * 8]);
#pragma unroll
    for (int ni = 0; ni < 2; ++ni) {
      const int tl = n0 + ni * 16 + l15;
      const int prow = (tl + (tl >> 3)) * 72;
#pragma unroll
      for (int ks = 0; ks < 2; ++ks)
        bfr[ni][ks] = *reinterpret_cast<const short8v*>(&BlF[prow + ks * 32 + quad * 8]);
    }
#pragma unroll
    for (int mi = 0; mi < 2; ++mi)
#pragma unroll
      for (int ni = 0; ni < 2; ++ni) {
        acc[mi][ni] = __builtin_amdgcn_mfma_f32_16x16x32_bf16(af[mi][0], bfr[ni][0], acc[mi][ni], 0, 0, 0);
        acc[mi][ni] = __builtin_amdgcn_mfma_f32_16x16x32_bf16(af[mi][1], bfr[ni][1], acc[mi][ni], 0, 0, 0);
      }
  }
#undef LOADK
  if (mode == 1) {
#pragma unroll
    for (int mi = 0; mi < 2; ++mi)
#pragma unroll
      for (int ni = 0; ni < 2; ++ni) {
        const int ob = mtile + m0 + mi * 16 + quad * 4;
        const int pg = ntile + n0 + ni * 16 + l15;
        *reinterpret_cast<f32x4*>((float*)outv + (size_t)pg * DD + ob) = acc[mi][ni];
      }
  } else {
    // ---- epilogue via LDS: scatter acc -> [64 ch][72-stride tok tile], read back coalesced ----
    __syncthreads();                     // all waves done reading BlF
#pragma unroll
    for (int mi = 0; mi < 2; ++mi)
#pragma unroll
      for (int ni = 0; ni < 2; ++ni)
#pragma unroll
        for (int r = 0; r < 4; ++r)
          BlF[(m0 + mi * 16 + quad * 4 + r) * 72 + n0 + ni * 16 + l15] = f2bf(acc[mi][ni][r]);
    __syncthreads();
    const int orow = t >> 2, oc0 = (t & 3) * 16;
    const uint4 o0 = *reinterpret_cast<const uint4*>(&BlF[orow * 72 + oc0]);
    const uint4 o1 = *reinterpret_cast<const uint4*>(&BlF[orow * 72 + oc0 + 8]);
    u16* dstb = (u16*)outv + ((size_t)(bb * DD + mtile + orow)) * PP + pq0 + oc0;
    *reinterpret_cast<uint4*>(dstb) = o0;
    *reinterpret_cast<uint4*>(dstb + 8) = o1;
  }
}

// ---------------- xdown GEMM with register prefetch ----------------
// grid 256: 16-token N-tiles. A = wXdB 64x768 (rows 48+ zero), i = ((p&31)>>4)*512 + (p>>5)*16 + (p&15)
__global__ __launch_bounds__(256) void xdgemm_k(const u16* __restrict__ A,
                                                const u16* __restrict__ Ycm,
                                                u16* __restrict__ xpA) {
  __shared__ u16 Al[64][72];
  __shared__ u16 Bl[16][72];
  const int t = threadIdx.x;
  const int ntile = blockIdx.x * 16;
  const int bb = ntile >> 10, pq0 = ntile & 1023;
  const int wid = t >> 6, lane = t & 63, l15 = lane & 15, quad = lane >> 4;
  f32x4 acc = (f32x4){0.f, 0.f, 0.f, 0.f};
  const int arow = t >> 2, aks = (t & 3) * 16;
  const u16* ag = A + (size_t)arow * DD + aks;
  const int chp = t >> 3;          // 0..31 channel-pairs (ch = 2*chp)
  const int tk0 = (t & 7) * 2;     // tokens tk0, tk0+1
  const u16* bg0 = Ycm + ((size_t)(bb * DD + chp * 2)) * PP + pq0 + tk0;
  uint4 pa0, pa1;
  u32 pb0, pb1;
#define LOADX(k0)                                                     \
  {                                                                   \
    pa0 = *reinterpret_cast<const uint4*>(ag + (k0));                 \
    pa1 = *reinterpret_cast<const uint4*>(ag + (k0) + 8);             \
    pb0 = *reinterpret_cast<const u32*>(bg0 + (size_t)(k0) * PP);     \
    pb1 = *reinterpret_cast<const u32*>(bg0 + (size_t)((k0) + 1) * PP); \
  }
  LOADX(0);
  for (int k0 = 0; k0 < DD; k0 += 64) {
    __syncthreads();                     // prev compute done reading LDS
    *reinterpret_cast<uint4*>(&Al[arow][aks]) = pa0;
    *reinterpret_cast<uint4*>(&Al[arow][aks + 8]) = pa1;
    *reinterpret_cast<u32*>(&Bl[tk0][chp * 2]) = (pb0 & 0xffffu) | (pb1 << 16);
    *reinterpret_cast<u32*>(&Bl[tk0 + 1][chp * 2]) = (pb0 >> 16) | (pb1 & 0xffff0000u);
    __syncthreads();                     // LDS ready
    if (k0 + 64 < DD) LOADX(k0 + 64);    // prefetch flies under compute
#pragma unroll
    for (int ks = 0; ks < 2; ++ks) {
      const short8v af = *reinterpret_cast<const short8v*>(&Al[wid * 16 + l15][ks * 32 + quad * 8]);
      const short8v bf = *reinterpret_cast<const short8v*>(&Bl[l15][ks * 32 + quad * 8]);
      acc = __builtin_amdgcn_mfma_f32_16x16x32_bf16(af, bf, acc, 0, 0, 0);
    }
  }
#undef LOADX
  const int pq = pq0 + l15;
  const int i = ((pq & 31) >> 4) * 512 + (pq >> 5) * 16 + (pq & 15);
  u16* dst = xpA + ((size_t)(bb * 1024 + i)) * 64 + wid * 16 + quad * 4;
  *reinterpret_cast<uint2*>(dst) = make_uint2(pk_trunc(acc[1], acc[0]), pk_trunc(acc[3], acc[2]));
}

// ---------------- depthwise 7x7 + bias, bf16 -> bf16 ----------------
__global__ __launch_bounds__(256) void dwconv7_k(const u16* __restrict__ x,
                                                 const float* __restrict__ wgt,
                                                 const float* __restrict__ bias,
                                                 u16* __restrict__ y) {
  const int bc = blockIdx.x;
  const int c = bc % DD;
  __shared__ float tile[38 * 38];
  __shared__ float wl[49];
  __shared__ float bsh[1];
  const int t = threadIdx.x;
  for (int i = t; i < 38 * 38; i += 256) tile[i] = 0.f;
  __syncthreads();
  const u16* xr = x + (size_t)bc * PP;
  for (int i = t; i < 512; i += 256) {
    const u32 v = reinterpret_cast<const u32*>(xr)[i];
    const int p0 = i * 2;
    const int h = p0 >> 5, w = p0 & 31;
    tile[(h + 3) * 38 + w + 3] = b2f((u16)v);
    tile[(h + 3) * 38 + w + 4] = b2f((u16)(v >> 16));
  }
  if (t < 49) wl[t] = wgt[c * 49 + t];
  if (t == 0) bsh[0] = bias[c];
  __syncthreads();
  u16* yo = y + (size_t)bc * PP;
  const int w = t & 31, hb = t >> 5;         // hb 0..7 -> rows hb*4 .. hb*4+3
  const float bv = bsh[0];
  float a0 = bv, a1 = bv, a2 = bv, a3 = bv;
#pragma unroll
  for (int rr = 0; rr < 10; ++rr) {          // input rows hb*4+rr
    float row[7];
#pragma unroll
    for (int kw = 0; kw < 7; ++kw) row[kw] = tile[(hb * 4 + rr) * 38 + w + kw];
    if (rr < 7) {
#pragma unroll
      for (int kw = 0; kw < 7; ++kw) a0 = fmaf(wl[rr * 7 + kw], row[kw], a0);
    }
    if (rr >= 1 && rr < 8) {
#pragma unroll
      for (int kw = 0; kw < 7; ++kw) a1 = fmaf(wl[(rr - 1) * 7 + kw], row[kw], a1);
    }
    if (rr >= 2 && rr < 9) {
#pragma unroll
      for (int kw = 0; kw < 7; ++kw) a2 = fmaf(wl[(rr - 2) * 7 + kw], row[kw], a2);
    }
    if (rr >= 3) {
#pragma unroll
      for (int kw = 0; kw < 7; ++kw) a3 = fmaf(wl[(rr - 3) * 7 + kw], row[kw], a3);
    }
  }
  yo[(hb * 4 + 0) * 32 + w] = f2bf(a0);
  yo[(hb * 4 + 1) * 32 + w] = f2bf(a1);
  yo[(hb * 4 + 2) * 32 + w] = f2bf(a2);
  yo[(hb * 4 + 3) * 32 + w] = f2bf(a3);
}

// ---------------- depthwise 3x3 (no bias) + x*relu(x), bf16 -> bf16 ----------------
__global__ __launch_bounds__(256) void dwconv3_k(const u16* __restrict__ x,
                                                 const float* __restrict__ wgt,
                                                 u16* __restrict__ y) {
  const int bc = blockIdx.x;
  const int c = bc % DD;
  __shared__ float tile[34 * 34];
  __shared__ float wl[9];
  const int t = threadIdx.x;
  for (int i = t; i < 34 * 34; i += 256) tile[i] = 0.f;
  __syncthreads();
  const u16* xr = x + (size_t)bc * PP;
  for (int i = t; i < 512; i += 256) {
    const u32 v = reinterpret_cast<const u32*>(xr)[i];
    const int p0 = i * 2;
    const int h = p0 >> 5, w = p0 & 31;
    tile[(h + 1) * 34 + w + 1] = b2f((u16)v);
    tile[(h + 1) * 34 + w + 2] = b2f((u16)(v >> 16));
  }
  if (t < 9) wl[t] = wgt[c * 9 + t];
  __syncthreads();
  u16* yo = y + (size_t)bc * PP;
  const int w = t & 31, hb = t >> 5;
  float a0 = 0.f, a1 = 0.f, a2 = 0.f, a3 = 0.f;
#pragma unroll
  for (int rr = 0; rr < 6; ++rr) {
    float row[3];
#pragma unroll
    for (int kw = 0; kw < 3; ++kw) row[kw] = tile[(hb * 4 + rr) * 34 + w + kw];
    if (rr < 3) {
#pragma unroll
      for (int kw = 0; kw < 3; ++kw) a0 = fmaf(wl[rr * 3 + kw], row[kw], a0);
    }
    if (rr >= 1 && rr < 4) {
#pragma unroll
      for (int kw = 0; kw < 3; ++kw) a1 = fmaf(wl[(rr - 1) * 3 + kw], row[kw], a1);
    }
    if (rr >= 2 && rr < 5) {
#pragma unroll
      for (int kw = 0; kw < 3; ++kw) a2 = fmaf(wl[(rr - 2) * 3 + kw], row[kw], a2);
    }
    if (rr >= 3) {
#pragma unroll
      for (int kw = 0; kw < 3; ++kw) a3 = fmaf(wl[(rr - 3) * 3 + kw], row[kw], a3);
    }
  }
  const float r0 = a0 > 0.f ? a0 * a0 : 0.f;
  const float r1 = a1 > 0.f ? a1 * a1 : 0.f;
  const float r2 = a2 > 0.f ? a2 * a2 : 0.f;
  const float r3 = a3 > 0.f ? a3 * a3 : 0.f;
  yo[(hb * 4 + 0) * 32 + w] = f2bf(r0);
  yo[(hb * 4 + 1) * 32 + w] = f2bf(r1);
  yo[(hb * 4 + 2) * 32 + w] = f2bf(r2);
  yo[(hb * 4 + 3) * 32 + w] = f2bf(r3);
}

// ---------------- producer/consumer fused scan (best-measured structure, unchanged) ------------
#define ACT_SWZ(row, col) ((col) ^ (((((col) >> 6) ^ (row)) & 7) << 3))
#define PSWZ(r) ((((r) ^ ((r) >> 3)) & 3) << 3)

__device__ __forceinline__ void produce_half(u16* __restrict__ actbuf,
                                             const u16* __restrict__ ab,
                                             const short8v bw[2][2],
                                             int l15, int quad, int g) {
#pragma unroll
  for (int mt = 0; mt < 8; ++mt) {
    const u16* ar = ab + (mt * 16 + l15) * 64 + quad * 8;
    const short8v a0 = *reinterpret_cast<const short8v*>(ar);
    const short8v a1 = *reinterpret_cast<const short8v*>(ar + 32);
    f32x4 acc0 = {0.f, 0.f, 0.f, 0.f}, acc1 = {0.f, 0.f, 0.f, 0.f};
    acc0 = __builtin_amdgcn_mfma_f32_16x16x32_bf16(a0, bw[0][0], acc0, 0, 0, 0);
    acc0 = __builtin_amdgcn_mfma_f32_16x16x32_bf16(a1, bw[0][1], acc0, 0, 0, 0);
    acc1 = __builtin_amdgcn_mfma_f32_16x16x32_bf16(a0, bw[1][0], acc1, 0, 0, 0);
    acc1 = __builtin_amdgcn_mfma_f32_16x16x32_bf16(a1, bw[1][1], acc1, 0, 0, 0);
    const int qb = g * 128 + mt * 16 + quad * 4;      // LOCAL token col in [0,512)
    const int cs = ACT_SWZ(l15, qb);
    *reinterpret_cast<uint2*>(&actbuf[l15 * 512 + cs]) =
        make_uint2(pk_trunc(acc0[1], acc0[0]), pk_trunc(acc0[3], acc0[2]));
    if (l15 < 8)
      *reinterpret_cast<uint2*>(&actbuf[(16 + l15) * 512 + cs]) =
          make_uint2(pk_trunc(acc1[1], acc1[0]), pk_trunc(acc1[3], acc1[2]));
  }
}

__device__ __forceinline__ void consume_half(const u16* __restrict__ actbuf,
                                             const u16* __restrict__ planeTc,
                                             const u16* __restrict__ y2row,
                                             u16* __restrict__ outpc,
                                             float mw, int dpair, int cs2, int d, int h, int half) {
  __builtin_amdgcn_s_setprio(1);
  const int k = dpair * 2 + d;
  const int hc = half * 2 + cs2;
  const int colb = h * 16 + cs2 * 8;
  const int wst = dpair ? (24 - hc * 8) : (hc * 8);
  short8v vPr;
  if (d == 0) vPr = *reinterpret_cast<const short8v*>(y2row + h * 32 + wst);
  else        vPr = *reinterpret_cast<const short8v*>(planeTc + h * 40 + (wst ^ PSWZ(h)));
  short8v vPe;
  {
    const u32* s = (const u32*)&vPr;
    u32* dq = (u32*)&vPe;
    if (dpair) {
      dq[0] = (s[3] >> 16) | (s[3] << 16);
      dq[1] = (s[2] >> 16) | (s[2] << 16);
      dq[2] = (s[1] >> 16) | (s[1] << 16);
      dq[3] = (s[0] >> 16) | (s[0] << 16);
    } else {
      dq[0] = s[0]; dq[1] = s[1]; dq[2] = s[2]; dq[3] = s[3];
    }
  }
#define ACTP(row) (*reinterpret_cast<const short8v*>(&actbuf[(row) * 512 + ACT_SWZ((row), colb)]))
  const short8v vGl = ACTP(0 + k);
  const short8v vGm = ACTP(4 + k);
  const short8v vGr = ACTP(8 + k);
  const short8v vL  = ACTP(12 + k);
  const short8v vU  = ACTP(16 + k);
  const short8v vD  = ACTP(20 + k);
#undef ACTP
  const bool top = (h == 0), bot = (h == 31);
  float H = 0.f, prev = 0.f;
  u32 ox[4];
#pragma unroll
  for (int j = 0; j < 8; ++j) {
    float el = __expf(-ex8(vGl, j));
    const float em = __expf(-ex8(vGm, j));
    float er = __expf(-ex8(vGr, j));
    if (top) el = 1e30f;
    if (bot) er = 1e30f;
    const float pl2 = 1.f + el, pm = 1.f + em, pr = 1.f + er;
    const float ul = pm * pr, um = pl2 * pr, ur = pl2 * pm;
    const float rcpS = __builtin_amdgcn_rcpf(ul + um + ur);
    const float xv = ex8(vPe, j);
    const float Lx = ex8(vL, j) * xv;
    const float up = dpp_shr1(H);
    const float dn = dpp_shl1(H);
    H = fmaf(ul * rcpS, up, fmaf(um * rcpS, H, fmaf(ur * rcpS, dn, Lx)));
    float part = fmaf(H, ex8(vU, j), xv * ex8(vD, j)) * mw;
    part = xhalf_sum(part);
    if (j & 1) ox[j >> 1] = pk_trunc(part, prev);
    else prev = part;
  }
  if (d == 0) {
    uint4 o;
    o.x = ox[0]; o.y = ox[1]; o.z = ox[2]; o.w = ox[3];
    *reinterpret_cast<uint4*>(&outpc[h * 64 + dpair * 32 + ((hc * 8) ^ ((h & 3) << 3))]) = o;
  }
  __builtin_amdgcn_s_setprio(0);
}

__global__ __launch_bounds__(512, 4) void scan_k(const u16* __restrict__ y2b,
                                                 const u16* __restrict__ xpA,
                                                 const u16* __restrict__ wB,
                                                 const float* __restrict__ mwp,
                                                 u16* __restrict__ out1) {
  const int bc2 = blockIdx.x;            // 0..1535
  const int b = bc2 / 384;
  const int cpair = bc2 - b * 384;
  const int c0 = cpair * 2;
  __shared__ __align__(16) u16 actA[24 * 512];      // 24,576 B
  __shared__ __align__(16) u16 actB[24 * 512];      // 24,576 B
  __shared__ __align__(16) u16 planeT[2][1280];     //  5,120 B  [ch][w:32][h:40 swz]
  __shared__ __align__(16) u16 outp[2][32 * 64];    //  8,192 B  (total 62,464)
  const int t = threadIdx.x;
  const int wid = t >> 6, lane = t & 63, l15 = lane & 15, quad = lane >> 4;
  const int ch = wid >> 2;               // wave's channel (0/1)
  const int g = wid & 3;                 // producer index within group
  const int dpair = g & 1, cs2 = g >> 1;
  const int d = lane >> 5, h = lane & 31;
  const int c = c0 + ch;
  const int bc = b * DD + c;
  // ---- prologue: transposed planes for both channels ----
  {
    const int pch = t >> 8, idx = t & 255;
    const u16* yp = y2b + (size_t)(b * DD + c0 + pch) * PP;
#pragma unroll
    for (int i2 = 0; i2 < 2; ++i2) {
      const int i = idx + i2 * 256;
      const u32 v = reinterpret_cast<const u32*>(yp)[i];
      const int p0 = i * 2;
      const int hh = p0 >> 5, ww = p0 & 31;
      planeT[pch][ww * 40 + (hh ^ PSWZ(ww))] = (u16)v;
      planeT[pch][(ww + 1) * 40 + (hh ^ PSWZ(ww + 1))] = (u16)(v >> 16);
    }
  }
  // ---- per-channel projection weights ----
  const u16* wc = wB + (size_t)c * 2048;
  short8v bw[2][2];
#pragma unroll
  for (int nt = 0; nt < 2; ++nt)
#pragma unroll
    for (int ks = 0; ks < 2; ++ks)
      bw[nt][ks] = *reinterpret_cast<const short8v*>(wc + (nt * 16 + l15) * 64 + ks * 32 + quad * 8);
  const u16* xb = xpA + ((size_t)(b * 1024)) * 64;
  const u16* y2row = y2b + (size_t)bc * PP;
  const float mw = mwp[dpair * 2 + d];
  // ---- prologue produce: waves0-3 -> actA = c0 half0 ----
  if (ch == 0) produce_half(actA, xb + (size_t)(g * 128) * 64, bw, l15, quad, g);
  __syncthreads();   // BAR0: planes + actA(c0h0)
  // ---- R1 ----
  if (ch == 0) consume_half(actA, planeT[0], y2row, outp[0], mw, dpair, cs2, d, h, 0);
  else         produce_half(actB, xb + (size_t)(g * 128) * 64, bw, l15, quad, g);
  __syncthreads();   // BAR1
  // ---- R2 ----
  if (ch == 1) consume_half(actB, planeT[1], y2row, outp[1], mw, dpair, cs2, d, h, 0);
  else         produce_half(actA, xb + (size_t)(512 + g * 128) * 64, bw, l15, quad, g);
  __syncthreads();   // BAR2
  // ---- R3 ----
  if (ch == 0) consume_half(actA, planeT[0], y2row, outp[0], mw, dpair, cs2, d, h, 1);
  else         produce_half(actB, xb + (size_t)(512 + g * 128) * 64, bw, l15, quad, g);
  __syncthreads();   // BAR3
  // ---- R4 ----
  if (ch == 1) consume_half(actB, planeT[1], y2row, outp[1], mw, dpair, cs2, d, h, 1);
  __syncthreads();   // BAR4
  // ---- combine both channels, full-line coalesced stores ----
  const int hh2 = t >> 4, wp = t & 15;
  const int wsw = (wp * 2) ^ ((hh2 & 3) << 3);
#pragma unroll
  for (int cc = 0; cc < 2; ++cc) {
    const u32 u0 = *reinterpret_cast<const u32*>(&outp[cc][hh2 * 64 + wsw]);
    const u32 u1 = *reinterpret_cast<const u32*>(&outp[cc][hh2 * 64 + 32 + wsw]);
    const float v0 = b2f((u16)u0) + b2f((u16)u1);
    const float v1 = b2f((u16)(u0 >> 16)) + b2f((u16)(u1 >> 16));
    *reinterpret_cast<u32*>(out1 + (size_t)(b * DD + c0 + cc) * PP + hh2 * 32 + wp * 2) =
        pk_trunc(v1, v0);
  }
}

extern "C" void kernel_launch(void* const* d_in, const int* in_sizes, int n_in,
                              void* d_out, int out_size, void* d_ws, size_t ws_size,
                              hipStream_t stream) {
  const float* hs   = (const float*)d_in[0];
  const float* nw   = (const float*)d_in[1];
  const float* nb   = (const float*)d_in[2];
  const float* win  = (const float*)d_in[3];
  const float* c7w  = (const float*)d_in[4];
  const float* c7b  = (const float*)d_in[5];
  const float* xdw  = (const float*)d_in[6];
  const float* wupw = (const float*)d_in[7];
  const float* lupw = (const float*)d_in[8];
  const float* uupw = (const float*)d_in[9];
  const float* dcow = (const float*)d_in[10];
  const float* mww  = (const float*)d_in[11];
  const float* wout = (const float*)d_in[12];
  const float* odw  = (const float*)d_in[13];
  const float* wprj = (const float*)d_in[14];
  float* out0 = (float*)d_out;
  float* shortcut = out0 + (size_t)NTOK * DD;

  char* ws = (char*)d_ws;
  u16* lnA    = (u16*)(ws + 0);            // 6,291,456
  u16* wInB   = (u16*)(ws + 6291456);      // 1,179,648
  u16* wOutB  = (u16*)(ws + 7471104);      // 1,179,648
  u16* wPrjB  = (u16*)(ws + 8650752);      // 1,179,648
  u16* wB     = (u16*)(ws + 9830400);      // 3,145,728
  u16* wXdB   = (u16*)(ws + 12976128);     //    98,304
  u16* xpA    = (u16*)(ws + 13074432);     //   524,288
  u16* y1b    = (u16*)(ws + 13598720);     // 6,291,456  y1 (gemm1->dw7); later y3 (gemm2->dw3)
  u16* y2b    = (u16*)(ws + 19890176);     // 6,291,456  y2 (dw7 -> xdgemm+scan)
  u16* out1   = (u16*)(ws + 26181632);     // 6,291,456  scan->gemm2; later y4 (dw3->gemm3)
  u16* y3b    = y1b;
  u16* y4b    = out1;

  prep_ln_k<<<6640, 256, 0, stream>>>(hs, nw, nb, lnA, shortcut,
                                      win, wInB, wout, wOutB, wprj, wPrjB,
                                      xdw, wXdB, wupw, lupw, uupw, dcow, wB);
  gemm_bf16<0><<<dim3(64, 12), 256, 0, stream>>>(wInB, lnA, y1b, 3);       // in_proj -> y1 bf16 ch-major
  dwconv7_k<<<3072, 256, 0, stream>>>(y1b, c7w, c7b, y2b);                 // y2 bf16 ch-major
  xdgemm_k<<<256, 256, 0, stream>>>(wXdB, y2b, xpA);                       // xdown -> xpA (h-major rows)
  scan_k<<<1536, 512, 0, stream>>>(y2b, xpA, wB, mww, out1);               // out1 bf16 ch-major (P/C)
  gemm_bf16<1><<<dim3(64, 12), 256, 0, stream>>>(wOutB, out1, y3b, 3);     // outconv -> y3 bf16 ch-major
  dwconv3_k<<<3072, 256, 0, stream>>>(y3b, odw, y4b);                      // dw3 + x*relu(x) -> y4 ch-major
  gemm_bf16<1><<<dim3(64, 12), 256, 0, stream>>>(wPrjB, y4b, out0, 1);     // outproj -> out f32 [b][t][d]
}